// Round 14
// baseline (1508.661 us; speedup 1.0000x reference)
//
#include <hip/hip_runtime.h>

#define B_ 32
#define P_ 196
#define T_ 32
#define E_ 512
#define H_ 512
#define A_ 256
#define V_ 30000
#define FEAT_ 2048

typedef unsigned short u16;
typedef __attribute__((ext_vector_type(8))) short bf16x8;
typedef __attribute__((ext_vector_type(4))) float fx4;

#define MFMA16 __builtin_amdgcn_mfma_f32_16x16x32_bf16

__device__ __forceinline__ u16 f2b(float f){
  unsigned u = __builtin_bit_cast(unsigned, f);
  u += 0x7FFFu + ((u >> 16) & 1u);
  return (u16)(u >> 16);
}
__device__ __forceinline__ float b2f(u16 h){
  unsigned u = ((unsigned)h) << 16;
  return __builtin_bit_cast(float, u);
}
__device__ __forceinline__ float sigm(float x){ return 1.f/(1.f + __expf(-x)); }

// ================= merged prep: all packs/converts/gather in ONE launch =================
// block ranges (256 thr each):
//   [0,12288)      pack_g0        (6144*512 elems)
//   [12288,20480)  pack_w1p       (32*128*512)
//   [20480,24230)  pack_w2        (960000 i, 8 elems/i)
//   [24230,24742)  convert Wad    (131072 i)
//   [24742,24806)  convert We     (16384 i)
//   [24806,24870)  convert W1     (16384 i)
//   [24870,25126)  pack_wd2       (65536 i)
//   [25126,25134)  bias0
//   [25134,25142)  bias1
//   [25142,25398)  gather         (4 rows/block)
#define PREP_BLOCKS 25398
__global__ void k_prep(const float* __restrict__ Wad, const float* __restrict__ We,
                       const float* __restrict__ W1f, const float* __restrict__ W2f,
                       const float* __restrict__ Wd,
                       const float* __restrict__ Wih0, const float* __restrict__ Whh0,
                       const float* __restrict__ Wih1, const float* __restrict__ Whh1,
                       const float* __restrict__ bih0, const float* __restrict__ bhh0,
                       const float* __restrict__ bih1, const float* __restrict__ bhh1,
                       const float* __restrict__ emb, const int* __restrict__ cap,
                       u16* __restrict__ Wad16, u16* __restrict__ We16,
                       u16* __restrict__ W1_16, u16* __restrict__ W2pk,
                       unsigned* __restrict__ Wd2, u16* __restrict__ Wg0pk,
                       u16* __restrict__ W1ppk, float* __restrict__ bias0p,
                       float* __restrict__ bias1p, u16* __restrict__ embs16){
  int bid = blockIdx.x, tid = threadIdx.x;
  if (bid < 12288){                                   // ---- pack_g0
    int eid = bid*256 + tid;
    int j = eid & 7, l = (eid >> 3) & 63, frag = eid >> 9;
    int ks = frag % 12; int rest = frag / 12;
    int kw = rest & 3, q = (rest >> 2) & 3, s = rest >> 4;
    int n = q*512 + s*16 + (l & 15);
    int k = kw*384 + ks*32 + ((l >> 4) << 3) + j;
    float v = (k < 1024) ? Wih0[(size_t)n*1024 + k] : Whh0[(size_t)n*512 + (k - 1024)];
    Wg0pk[eid] = f2b(v);
  } else if (bid < 20480){                            // ---- pack_w1p
    int eid = (bid-12288)*256 + tid;
    int j = eid & 7, l = (eid >> 3) & 63, f = eid >> 9;
    int nf = f & 127, s = f >> 7;
    int np = nf*16 + (l & 15);
    int k = ((l >> 4) << 3) + j;
    int orig = ((np >> 4) & 3)*512 + (np >> 6)*16 + (np & 15);
    float v = (k < 16) ? Wih1[(size_t)orig*512 + s*16 + k]
                       : Whh1[(size_t)orig*512 + s*16 + (k - 16)];
    W1ppk[eid] = f2b(v);
  } else if (bid < 24230){                            // ---- pack_w2
    int i = (bid-20480)*256 + tid;
    int l = i & 63, kc = (i >> 6) & 7, nf = i >> 9;
    int row = nf*16 + (l & 15);
    int col = kc*32 + (l >> 4)*8;
    const float4* s = (const float4*)(W2f + (size_t)row*256 + col);
    float4 a = s[0], b = s[1];
    ushort4* d = (ushort4*)(W2pk + (size_t)i*8);
    d[0] = make_ushort4(f2b(a.x), f2b(a.y), f2b(a.z), f2b(a.w));
    d[1] = make_ushort4(f2b(b.x), f2b(b.y), f2b(b.z), f2b(b.w));
  } else if (bid < 24742){                            // ---- convert Wad
    int i = (bid-24230)*256 + tid;
    const float4* s = (const float4*)Wad + (size_t)i*2;
    float4 a = s[0], b = s[1];
    ushort4* d = (ushort4*)Wad16 + (size_t)i*2;
    d[0] = make_ushort4(f2b(a.x), f2b(a.y), f2b(a.z), f2b(a.w));
    d[1] = make_ushort4(f2b(b.x), f2b(b.y), f2b(b.z), f2b(b.w));
  } else if (bid < 24806){                            // ---- convert We
    int i = (bid-24742)*256 + tid;
    const float4* s = (const float4*)We + (size_t)i*2;
    float4 a = s[0], b = s[1];
    ushort4* d = (ushort4*)We16 + (size_t)i*2;
    d[0] = make_ushort4(f2b(a.x), f2b(a.y), f2b(a.z), f2b(a.w));
    d[1] = make_ushort4(f2b(b.x), f2b(b.y), f2b(b.z), f2b(b.w));
  } else if (bid < 24870){                            // ---- convert W1
    int i = (bid-24806)*256 + tid;
    const float4* s = (const float4*)W1f + (size_t)i*2;
    float4 a = s[0], b = s[1];
    ushort4* d = (ushort4*)W1_16 + (size_t)i*2;
    d[0] = make_ushort4(f2b(a.x), f2b(a.y), f2b(a.z), f2b(a.w));
    d[1] = make_ushort4(f2b(b.x), f2b(b.y), f2b(b.z), f2b(b.w));
  } else if (bid < 25126){                            // ---- pack_wd2
    int i = (bid-24870)*256 + tid;
    int n = i & 255, kp = i >> 8;
    unsigned lo = f2b(Wd[n*512 + 2*kp]);
    unsigned hi = f2b(Wd[n*512 + 2*kp + 1]);
    Wd2[i] = lo | (hi << 16);
  } else if (bid < 25134){                            // ---- bias0
    int n = (bid-25126)*256 + tid;
    int c = n & 15, q = (n >> 4) & 3, s = n >> 6;
    int orig = q*512 + s*16 + c;
    bias0p[n] = bih0[orig] + bhh0[orig];
  } else if (bid < 25142){                            // ---- bias1
    int n = (bid-25134)*256 + tid;
    int c = n & 15, q = (n >> 4) & 3, s = n >> 6;
    int orig = q*512 + s*16 + c;
    bias1p[n] = bih1[orig] + bhh1[orig];
  } else {                                            // ---- gather (4 rows/block)
    int r = (bid-25142)*4 + (tid >> 6), l = tid & 63;
    int t = r >> 5, b = r & 31;
    int c = cap[b*T_ + t];
    const float4* s = (const float4*)(emb + (size_t)c*E_) + l*2;
    float4 a = s[0], bb = s[1];
    ushort4* d = (ushort4*)(embs16 + (size_t)r*E_) + l*2;
    d[0] = make_ushort4(f2b(a.x), f2b(a.y), f2b(a.z), f2b(a.w));
    d[1] = make_ushort4(f2b(bb.x), f2b(bb.y), f2b(bb.z), f2b(bb.w));
  }
}

// ============ encoder GEMMs with XCD-panel swizzle ============
// flat grid = 8 * NQ * ceil(MP/8); decode so all NQ n-tiles of one A-panel share f%8
// (same XCD under round-robin) -> A panel fetched once per XCD.
template<int MODE, int BM, int BN, int KS, int NQ>
__launch_bounds__(256)
__global__ void k_gemm(const u16* __restrict__ A, const u16* __restrict__ W,
                       const float* __restrict__ bias, u16* __restrict__ outB,
                       int M, int N, int K){
  constexpr int NI = BN/32, MI = BM/32, SEGS = KS/8;
  __shared__ __align__(16) u16 As[BM][KS+8];
  __shared__ __align__(16) u16 Bs[BN][KS+8];
  int f = blockIdx.x;
  int p8 = f & 7; int rest = f >> 3;
  int q = rest % NQ; int pHigh = rest / NQ;
  int p = pHigh*8 + p8;
  if (p*BM >= M) return;
  int m0 = p*BM, n0 = q*BN;
  int tid = threadIdx.x;
  int l = tid & 63, w = tid >> 6;
  int wr = w >> 1, wc = w & 1;
  fx4 acc[MI][NI];
  #pragma unroll
  for (int i=0;i<MI;i++)
    #pragma unroll
    for (int j=0;j<NI;j++) acc[i][j] = (fx4){0.f,0.f,0.f,0.f};
  int lr = l & 15, lg = l >> 4;
  for (int k0 = 0; k0 < K; k0 += KS){
    #pragma unroll
    for (int it=0; it<BM*SEGS/256; ++it){
      int flat = it*256 + tid, rr = flat/SEGS, cs = (flat%SEGS)*8;
      *(uint4*)&As[rr][cs] = *(const uint4*)(A + (size_t)(m0+rr)*K + k0 + cs);
    }
    uint4 z = {0u,0u,0u,0u};
    #pragma unroll
    for (int it=0; it<BN*SEGS/256; ++it){
      int flat = it*256 + tid, rr = flat/SEGS, cs = (flat%SEGS)*8;
      int rb = n0 + rr;
      *(uint4*)&Bs[rr][cs] = (rb < N) ? *(const uint4*)(W + (size_t)rb*K + k0 + cs) : z;
    }
    __syncthreads();
    #pragma unroll
    for (int kk=0; kk<KS/32; ++kk){
      bf16x8 av[MI], bv[NI];
      #pragma unroll
      for (int mi=0; mi<MI; mi++) av[mi] = *(const bf16x8*)&As[wr*(BM/2) + mi*16 + lr][kk*32 + lg*8];
      #pragma unroll
      for (int ni=0; ni<NI; ni++) bv[ni] = *(const bf16x8*)&Bs[wc*(BN/2) + ni*16 + lr][kk*32 + lg*8];
      #pragma unroll
      for (int mi=0; mi<MI; mi++)
        #pragma unroll
        for (int ni=0; ni<NI; ni++)
          acc[mi][ni] = MFMA16(av[mi], bv[ni], acc[mi][ni], 0, 0, 0);
    }
    __syncthreads();
  }
  #pragma unroll
  for (int mi=0; mi<MI; mi++)
    #pragma unroll
    for (int ni=0; ni<NI; ni++){
      int col = n0 + wc*(BN/2) + ni*16 + lr;
      if (col >= N) continue;
      float bvs = bias[col];
      #pragma unroll
      for (int reg=0; reg<4; reg++){
        int rowm = m0 + wr*(BM/2) + mi*16 + lg*4 + reg;
        float v = acc[mi][ni][reg] + bvs;
        if (MODE == 0) v = fmaxf(v, 0.f);
        outB[(size_t)rowm*N + col] = f2b(v);
      }
    }
}

// adapter: A is f32 (convert while staging), relu -> bf16; XCD swizzle
template<int BM, int BN, int KS, int NQ>
__launch_bounds__(256)
__global__ void k_gemmF(const float* __restrict__ A, const u16* __restrict__ W,
                        const float* __restrict__ bias, u16* __restrict__ outB,
                        int M, int N, int K){
  constexpr int NI = BN/32, MI = BM/32, SEGS = KS/8;
  __shared__ __align__(16) u16 As[BM][KS+8];
  __shared__ __align__(16) u16 Bs[BN][KS+8];
  int f = blockIdx.x;
  int p8 = f & 7; int rest = f >> 3;
  int q = rest % NQ; int pHigh = rest / NQ;
  int p = pHigh*8 + p8;
  if (p*BM >= M) return;
  int m0 = p*BM, n0 = q*BN;
  int tid = threadIdx.x;
  int l = tid & 63, w = tid >> 6;
  int wr = w >> 1, wc = w & 1;
  fx4 acc[MI][NI];
  #pragma unroll
  for (int i=0;i<MI;i++)
    #pragma unroll
    for (int j=0;j<NI;j++) acc[i][j] = (fx4){0.f,0.f,0.f,0.f};
  int lr = l & 15, lg = l >> 4;
  for (int k0 = 0; k0 < K; k0 += KS){
    #pragma unroll
    for (int it=0; it<BM*SEGS/256; ++it){
      int flat = it*256 + tid, rr = flat/SEGS, cs = (flat%SEGS)*8;
      const float4* s = (const float4*)(A + (size_t)(m0+rr)*K + k0 + cs);
      float4 a0 = s[0], a1 = s[1];
      *(ushort4*)&As[rr][cs]   = make_ushort4(f2b(a0.x), f2b(a0.y), f2b(a0.z), f2b(a0.w));
      *(ushort4*)&As[rr][cs+4] = make_ushort4(f2b(a1.x), f2b(a1.y), f2b(a1.z), f2b(a1.w));
    }
    #pragma unroll
    for (int it=0; it<BN*SEGS/256; ++it){
      int flat = it*256 + tid, rr = flat/SEGS, cs = (flat%SEGS)*8;
      *(uint4*)&Bs[rr][cs] = *(const uint4*)(W + (size_t)(n0+rr)*K + k0 + cs);
    }
    __syncthreads();
    #pragma unroll
    for (int kk=0; kk<KS/32; ++kk){
      bf16x8 av[MI], bv[NI];
      #pragma unroll
      for (int mi=0; mi<MI; mi++) av[mi] = *(const bf16x8*)&As[wr*(BM/2) + mi*16 + lr][kk*32 + lg*8];
      #pragma unroll
      for (int ni=0; ni<NI; ni++) bv[ni] = *(const bf16x8*)&Bs[wc*(BN/2) + ni*16 + lr][kk*32 + lg*8];
      #pragma unroll
      for (int mi=0; mi<MI; mi++)
        #pragma unroll
        for (int ni=0; ni<NI; ni++)
          acc[mi][ni] = MFMA16(av[mi], bv[ni], acc[mi][ni], 0, 0, 0);
    }
    __syncthreads();
  }
  #pragma unroll
  for (int mi=0; mi<MI; mi++)
    #pragma unroll
    for (int ni=0; ni<NI; ni++){
      int col = n0 + wc*(BN/2) + ni*16 + lr;
      float bvs = bias[col];
      #pragma unroll
      for (int reg=0; reg<4; reg++){
        int rowm = m0 + wr*(BM/2) + mi*16 + lg*4 + reg;
        float v = fmaxf(acc[mi][ni][reg] + bvs, 0.f);
        outB[(size_t)rowm*N + col] = f2b(v);
      }
    }
}

// ---------------- LayerNorm over 512 (bf16 in/out) ----------------
__global__ void k_ln1(const u16* __restrict__ pre, const float* __restrict__ g,
                      const float* __restrict__ bt, u16* __restrict__ enc){
  int row = blockIdx.x; int l = threadIdx.x;
  bf16x8 vv = *(const bf16x8*)(pre + (size_t)row*E_ + l*8);
  float x[8]; float s = 0.f;
  #pragma unroll
  for (int i=0;i<8;i++){ x[i] = b2f((u16)vv[i]); s += x[i]; }
  #pragma unroll
  for (int off=32; off; off>>=1) s += __shfl_xor(s, off, 64);
  float mean = s * (1.f/512.f);
  float vs = 0.f;
  #pragma unroll
  for (int i=0;i<8;i++){ float d = x[i]-mean; vs += d*d; }
  #pragma unroll
  for (int off=32; off; off>>=1) vs += __shfl_xor(vs, off, 64);
  float inv = rsqrtf(vs*(1.f/512.f) + 1e-5f);
  int c0 = l*8;
  u16 o[8];
  #pragma unroll
  for (int i=0;i<8;i++) o[i] = f2b((x[i]-mean)*inv*g[c0+i] + bt[c0+i]);
  ushort4* d = (ushort4*)(enc + (size_t)row*E_ + c0);
  d[0] = make_ushort4(o[0],o[1],o[2],o[3]);
  d[1] = make_ushort4(o[4],o[5],o[6],o[7]);
}

// ---------------- W1 GEMM + LN + relu -> hid[(u*32+b)*256] ----------------
__device__ __forceinline__ void w1ln_block(const u16* __restrict__ h1all,
    const u16* __restrict__ W1, const float* __restrict__ b1,
    const float* __restrict__ g1v, const float* __restrict__ bb1,
    u16* __restrict__ hid, int u, int tid, float* red2, float* mv){
  int l = tid & 63, w = tid >> 6, lr = l & 15, lg = l >> 4;
  fx4 acc[2] = {{0,0,0,0},{0,0,0,0}};
  for (int k0 = 0; k0 < 512; k0 += 32){
    bf16x8 bv  = *(const bf16x8*)(W1 + (size_t)(w*16+lr)*512 + k0 + lg*8);
    bf16x8 av0 = *(const bf16x8*)(h1all + ((size_t)lr*T_ + u)*512 + k0 + lg*8);
    bf16x8 av1 = *(const bf16x8*)(h1all + ((size_t)(16+lr)*T_ + u)*512 + k0 + lg*8);
    acc[0] = MFMA16(av0, bv, acc[0], 0,0,0);
    acc[1] = MFMA16(av1, bv, acc[1], 0,0,0);
  }
  int col = w*16 + lr;
  float bc = b1[col];
  float val[2][4], s1[2][4], s2[2][4];
  #pragma unroll
  for (int mi=0;mi<2;mi++)
    #pragma unroll
    for (int reg=0;reg<4;reg++){
      float v = acc[mi][reg] + bc;
      val[mi][reg] = v; s1[mi][reg] = v; s2[mi][reg] = v*v;
    }
  #pragma unroll
  for (int off=1; off<16; off<<=1){
    #pragma unroll
    for (int mi=0;mi<2;mi++)
      #pragma unroll
      for (int reg=0;reg<4;reg++){
        s1[mi][reg] += __shfl_xor(s1[mi][reg], off, 64);
        s2[mi][reg] += __shfl_xor(s2[mi][reg], off, 64);
      }
  }
  if (lr == 0){
    #pragma unroll
    for (int mi=0;mi<2;mi++)
      #pragma unroll
      for (int reg=0;reg<4;reg++){
        int row = mi*16 + lg*4 + reg;
        red2[(0*16 + w)*32 + row] = s1[mi][reg];
        red2[(16   + w)*32 + row] = s2[mi][reg];
      }
  }
  __syncthreads();
  if (tid < 64){
    int which = tid >> 5, row = tid & 31;
    float s = 0.f;
    #pragma unroll
    for (int ww=0; ww<16; ++ww) s += red2[(which*16 + ww)*32 + row];
    mv[which*32 + row] = s;
  }
  __syncthreads();
  #pragma unroll
  for (int mi=0;mi<2;mi++)
    #pragma unroll
    for (int reg=0;reg<4;reg++){
      int row = mi*16 + lg*4 + reg;
      float mean = mv[row] * (1.f/256.f);
      float var  = mv[32+row] * (1.f/256.f) - mean*mean;
      float inv  = rsqrtf(var + 1e-5f);
      float o = fmaxf((val[mi][reg]-mean)*inv*g1v[col] + bb1[col], 0.f);
      hid[((size_t)u*32 + row)*256 + col] = f2b(o);
    }
}

__launch_bounds__(1024)
__global__ void k_w1(const u16* __restrict__ h1all, const u16* __restrict__ W1_16,
                     const float* __restrict__ b1, const float* __restrict__ g1v,
                     const float* __restrict__ bb1, u16* __restrict__ hid16){
  __shared__ float red2[1024];
  __shared__ float mv[64];
  w1ln_block(h1all, W1_16, b1, g1v, bb1, hid16, blockIdx.x, threadIdx.x, red2, mv);
}

// ---------------- head: W2 frags in registers, loop u; full-line stores ----------------
__launch_bounds__(1024)
__global__ void k_head(const u16* __restrict__ hid, const u16* __restrict__ W2pk,
                       const float* __restrict__ b2, float* __restrict__ out){
  __shared__ __align__(16) union { u16 hA[32][264]; float Cs[32][260]; } S;
  int c = blockIdx.x, uh = blockIdx.y, tid = threadIdx.x;
  int l = tid & 63, w = tid >> 6, lr = l & 15, lg = l >> 4;
  int nf = c*16 + w;
  bool valid = nf < 1875;
  bf16x8 bw[8];
  if (valid){
    const u16* wp = W2pk + (size_t)nf*4096 + l*8;
    #pragma unroll
    for (int k0=0;k0<8;k0++) bw[k0] = *(const bf16x8*)(wp + k0*512);
  }
  int srow = tid >> 5, scc = (tid & 31)*8;
  int col0 = c*256 + scc;
  float bb[8];
  #pragma unroll
  for (int j=0;j<8;j++) bb[j] = (col0 + j < V_) ? b2[col0 + j] : 0.f;

  for (int ui=0; ui<16; ++ui){
    int u = uh*16 + ui;
    { int arow = tid >> 5, ak = (tid & 31)*8;
      *(uint4*)&S.hA[arow][ak] = *(const uint4*)(hid + ((size_t)u*32 + arow)*256 + ak); }
    __syncthreads();
    fx4 acc0 = {0,0,0,0}, acc1 = {0,0,0,0};
    if (valid){
      #pragma unroll
      for (int k0=0;k0<8;k0++){
        bf16x8 av0 = *(const bf16x8*)&S.hA[lr][k0*32 + lg*8];
        bf16x8 av1 = *(const bf16x8*)&S.hA[16+lr][k0*32 + lg*8];
        acc0 = MFMA16(av0, bw[k0], acc0, 0,0,0);
        acc1 = MFMA16(av1, bw[k0], acc1, 0,0,0);
      }
    }
    __syncthreads();
    #pragma unroll
    for (int reg=0; reg<4; ++reg){
      S.Cs[lg*4+reg][w*16+lr]    = acc0[reg];
      S.Cs[16+lg*4+reg][w*16+lr] = acc1[reg];
    }
    __syncthreads();
    if (col0 + 8 <= V_){
      float4 v0, v1;
      v0.x = fminf(fmaxf(S.Cs[srow][scc+0] + bb[0], -10.f), 10.f);
      v0.y = fminf(fmaxf(S.Cs[srow][scc+1] + bb[1], -10.f), 10.f);
      v0.z = fminf(fmaxf(S.Cs[srow][scc+2] + bb[2], -10.f), 10.f);
      v0.w = fminf(fmaxf(S.Cs[srow][scc+3] + bb[3], -10.f), 10.f);
      v1.x = fminf(fmaxf(S.Cs[srow][scc+4] + bb[4], -10.f), 10.f);
      v1.y = fminf(fmaxf(S.Cs[srow][scc+5] + bb[5], -10.f), 10.f);
      v1.z = fminf(fmaxf(S.Cs[srow][scc+6] + bb[6], -10.f), 10.f);
      v1.w = fminf(fmaxf(S.Cs[srow][scc+7] + bb[7], -10.f), 10.f);
      float* o = out + ((size_t)srow*T_ + u)*V_ + col0;
      *(float4*)o = v0; *(float4*)(o+4) = v1;
    }
    __syncthreads();
  }
}

// ---------------- LY: finish gates1(t-1)->h1; att2; attention; write [emb|ctx] ----------------
// (R8-proven version, verbatim)
__launch_bounds__(1024)
__global__ void k_ly(const float* __restrict__ part1, const float* __restrict__ bias1p,
                     float* __restrict__ c1buf, u16* __restrict__ h1all,
                     const unsigned* __restrict__ Wd2, const float* __restrict__ bd,
                     const u16* __restrict__ att1b, const u16* __restrict__ enc16,
                     const float* __restrict__ Wf, const float* __restrict__ bfp,
                     const u16* __restrict__ embs, u16* __restrict__ xh0cur, int t){
  int b = blockIdx.x, tid = threadIdx.x;
  int l = tid & 63, wid = tid >> 6;
  __shared__ float g1s[2048];
  __shared__ float h1s[512];
  __shared__ float a2p[4][256];
  __shared__ float a2[256], ev[256], red[8], wfv[256], bdv[256];
  __shared__ float cb[4][256][2];
  if (tid < 256){ wfv[tid] = Wf[tid]; bdv[tid] = bd[tid]; }
  float bf0 = bfp[0];

  if (t > 0){
    float acc0 = bias1p[tid], acc1 = bias1p[tid + 1024];
    #pragma unroll 4
    for (int s2=0; s2<32; ++s2){
      const float* pp = part1 + ((size_t)(s2*32 + b))*2048;
      acc0 += pp[tid];
      acc1 += pp[tid + 1024];
    }
    g1s[tid] = acc0; g1s[tid + 1024] = acc1;
    __syncthreads();
    if (tid < 512){
      int h = tid, s4 = h >> 4, c = h & 15, base = s4*64 + c;
      float gi = g1s[base], gf = g1s[base+16], gg = g1s[base+32], go = g1s[base+48];
      float cold = c1buf[b*512 + h];
      float cn = sigm(gf)*cold + sigm(gi)*tanhf(gg);
      c1buf[b*512 + h] = cn;
      float hn = sigm(go)*tanhf(cn);
      h1s[h] = hn;
      h1all[((size_t)b*T_ + (t-1))*512 + h] = f2b(hn);
    }
  } else {
    if (tid < 512) h1s[tid] = 0.f;
  }
  __syncthreads();
  if (t >= T_) return;

  {
    int n = tid & 255, kq = tid >> 8;
    float acc = 0.f;
    const unsigned* wp = Wd2 + (size_t)kq*64*256 + n;
    #pragma unroll 8
    for (int kp2 = 0; kp2 < 64; ++kp2){
      unsigned wv = wp[(size_t)kp2*256];
      int k0 = (kq*64 + kp2)*2;
      acc += h1s[k0]   * b2f((u16)(wv & 0xFFFFu))
           + h1s[k0+1] * b2f((u16)(wv >> 16));
    }
    a2p[kq][n] = acc;
  }
  __syncthreads();
  if (tid < 256) a2[tid] = a2p[0][tid] + a2p[1][tid] + a2p[2][tid] + a2p[3][tid] + bdv[tid];
  __syncthreads();
  for (int pi = 0; pi < 13; ++pi){
    int p = pi*16 + wid;
    if (p < P_){
      ushort4 av4 = *(const ushort4*)(att1b + (size_t)(b*P_ + p)*A_ + l*4);
      int j0 = l*4;
      float sum = fmaxf(b2f(av4.x)+a2[j0],  0.f)*wfv[j0]
                + fmaxf(b2f(av4.y)+a2[j0+1],0.f)*wfv[j0+1]
                + fmaxf(b2f(av4.z)+a2[j0+2],0.f)*wfv[j0+2]
                + fmaxf(b2f(av4.w)+a2[j0+3],0.f)*wfv[j0+3];
      #pragma unroll
      for (int off=32; off; off>>=1) sum += __shfl_xor(sum, off, 64);
      if (l == 0) ev[p] = sum + bf0;
    }
  }
  __syncthreads();
  if (tid < 256){
    float v = (tid < P_) ? ev[tid] : -1e30f;
    float m = v;
    #pragma unroll
    for (int off=32; off; off>>=1) m = fmaxf(m, __shfl_xor(m, off, 64));
    if (l == 0) red[wid] = m;
  }
  __syncthreads();
  float mg = fmaxf(fmaxf(red[0],red[1]), fmaxf(red[2],red[3]));
  if (tid < 256){
    float ex = (tid < P_) ? __expf(ev[tid] - mg) : 0.f;
    float ss = ex;
    #pragma unroll
    for (int off=32; off; off>>=1) ss += __shfl_xor(ss, off, 64);
    if (l == 0) red[4+wid] = ss;
    ev[tid] = ex;
  }
  __syncthreads();
  float inv = 1.f/(red[4]+red[5]+red[6]+red[7]);
  {
    int j = tid & 255, pq = tid >> 8;
    float A0 = 0.f, A1 = 0.f;
    const unsigned* ep = (const unsigned*)enc16 + ((size_t)b*P_ + pq*49)*256 + j;
    #pragma unroll 7
    for (int pi = 0; pi < 49; ++pi){
      unsigned vv = ep[(size_t)pi*256];
      float al = ev[pq*49 + pi];
      A0 += al * b2f((u16)(vv & 0xFFFFu));
      A1 += al * b2f((u16)(vv >> 16));
    }
    cb[pq][j][0] = A0; cb[pq][j][1] = A1;
  }
  __syncthreads();
  if (tid < 256){
    float c0 = (cb[0][tid][0]+cb[1][tid][0]+cb[2][tid][0]+cb[3][tid][0]) * inv;
    float c1 = (cb[0][tid][1]+cb[1][tid][1]+cb[2][tid][1]+cb[3][tid][1]) * inv;
    unsigned o = (unsigned)f2b(c0) | (((unsigned)f2b(c1)) << 16);
    *((unsigned*)(xh0cur + (size_t)b*1536 + 512) + tid) = o;
    ((unsigned*)(xh0cur + (size_t)b*1536))[tid] =
        ((const unsigned*)(embs + (size_t)(t*32+b)*E_))[tid];
  }
}

// ---------------- LX: gates0+cell0+gates1-partials; 3 barriers total ----------------
// wave = (q, kw4): all 4 gates in parallel, 4-way k-split, ONE reduce barrier-pair.
__launch_bounds__(1024)
__global__ void k_lx(const u16* __restrict__ xh0cur, u16* __restrict__ xh0nxt,
                     const u16* __restrict__ Wg0pk, const float* __restrict__ bias0p,
                     const u16* __restrict__ W1ppk, const u16* __restrict__ h1all,
                     float* __restrict__ c0buf, float* __restrict__ part1, int t){
  __shared__ float part4[4][4][32][16];   // [q][kw4][row][col] 32 KB
  __shared__ float gsum[4][32][16];       // 8 KB
  __shared__ __align__(16) u16 As[32][40];
  int tid = threadIdx.x, s = blockIdx.x;
  int l = tid & 63, kw = tid >> 6, lr = l & 15, lg = l >> 4;
  int q = kw >> 2, kw4 = kw & 3;

  // stage h1(t-1) slice early (independent of gates0)
  if (tid < 256){
    int bb = tid >> 3, kk = (tid & 7)*2;
    unsigned hv = 0;
    if (t > 0) hv = *(const unsigned*)(h1all + ((size_t)bb*T_ + (t-1))*512 + s*16 + kk);
    *(unsigned*)&As[bb][16+kk] = hv;
  }

  // gates0: 12 MFMAs per wave over kw4*384..+384, in two halves of 6 (VGPR cap)
  fx4 acc0 = (fx4){0,0,0,0}, acc1 = (fx4){0,0,0,0};
  const u16* wp = Wg0pk + (size_t)(((s*4+q)*4 + kw4)*12)*512 + l*8;
  #pragma unroll
  for (int half=0; half<2; ++half){
    bf16x8 a0[6], a1[6];
    #pragma unroll
    for (int ks=0; ks<6; ++ks){
      int k = kw4*384 + (half*6+ks)*32 + lg*8;
      a0[ks] = *(const bf16x8*)(xh0cur + (size_t)lr*1536 + k);
      a1[ks] = *(const bf16x8*)(xh0cur + (size_t)(16+lr)*1536 + k);
    }
    #pragma unroll
    for (int ks=0; ks<6; ++ks){
      bf16x8 bf8 = *(const bf16x8*)(wp + (half*6+ks)*512);
      acc0 = MFMA16(a0[ks], bf8, acc0, 0,0,0);
      acc1 = MFMA16(a1[ks], bf8, acc1, 0,0,0);
    }
  }
  #pragma unroll
  for (int reg=0;reg<4;reg++){
    part4[q][kw4][lg*4+reg][lr]    = acc0[reg];
    part4[q][kw4][16+lg*4+reg][lr] = acc1[reg];
  }
  __syncthreads();
  // reduce 4 partials + bias -> gsum (2048 entries, 2/thread)
  #pragma unroll
  for (int pp=0; pp<2; ++pp){
    int pid = tid + pp*1024;
    int q2 = pid >> 9, bb = (pid >> 4) & 31, c = pid & 15;
    gsum[q2][bb][c] = part4[q2][0][bb][c] + part4[q2][1][bb][c]
                    + part4[q2][2][bb][c] + part4[q2][3][bb][c]
                    + bias0p[s*64 + q2*16 + c];
  }
  __syncthreads();
  // cell0 -> h0(t) slice
  if (tid < 512){
    int bb = tid >> 4, c = tid & 15;
    int h = s*16 + c;
    float gi = gsum[0][bb][c], gf = gsum[1][bb][c], gg = gsum[2][bb][c], go = gsum[3][bb][c];
    float cold = c0buf[bb*512 + h];
    float cn = sigm(gf)*cold + sigm(gi)*tanhf(gg);
    c0buf[bb*512 + h] = cn;
    u16 hb = f2b(sigm(go)*tanhf(cn));
    xh0nxt[(size_t)bb*1536 + 1024 + h] = hb;
    As[bb][c] = hb;
  }
  __syncthreads();
  // gates1 partials: 16 waves x 8 nf
  bf16x8 pa0 = *(const bf16x8*)&As[lr][lg*8];
  bf16x8 pa1 = *(const bf16x8*)&As[16+lr][lg*8];
  #pragma unroll 2
  for (int i=0;i<8;i++){
    int nf = kw*8 + i;
    bf16x8 bf8 = *(const bf16x8*)(W1ppk + (size_t)(s*128 + nf)*512 + l*8);
    fx4 A0 = MFMA16(pa0, bf8, (fx4){0,0,0,0}, 0,0,0);
    fx4 A1 = MFMA16(pa1, bf8, (fx4){0,0,0,0}, 0,0,0);
    float* o = part1 + ((size_t)s*32)*2048 + nf*16 + lr;
    #pragma unroll
    for (int reg=0;reg<4;reg++){
      o[(size_t)(lg*4+reg)*2048]    = A0[reg];
      o[(size_t)(16+lg*4+reg)*2048] = A1[reg];
    }
  }
}

extern "C" void kernel_launch(void* const* d_in, const int* in_sizes, int n_in,
                              void* d_out, int out_size, void* d_ws, size_t ws_size,
                              hipStream_t stream){
  (void)in_sizes; (void)n_in; (void)out_size; (void)ws_size;
  const float* features = (const float*)d_in[0];
  const int*   captions = (const int*)d_in[1];
  const float* Wad  = (const float*)d_in[2];
  const float* bad  = (const float*)d_in[3];
  const float* g_ad = (const float*)d_in[4];
  const float* b_ad = (const float*)d_in[5];
  const float* We   = (const float*)d_in[6];
  const float* be   = (const float*)d_in[7];
  const float* Wd   = (const float*)d_in[8];
  const float* bd   = (const float*)d_in[9];
  const float* Wf   = (const float*)d_in[10];
  const float* bfp  = (const float*)d_in[11];
  const float* emb  = (const float*)d_in[12];
  const float* W_ih0 = (const float*)d_in[13];
  const float* W_hh0 = (const float*)d_in[14];
  const float* b_ih0 = (const float*)d_in[15];
  const float* b_hh0 = (const float*)d_in[16];
  const float* W_ih1 = (const float*)d_in[17];
  const float* W_hh1 = (const float*)d_in[18];
  const float* b_ih1 = (const float*)d_in[19];
  const float* b_hh1 = (const float*)d_in[20];
  const float* W1  = (const float*)d_in[21];
  const float* b1  = (const float*)d_in[22];
  const float* g1  = (const float*)d_in[23];
  const float* bb1 = (const float*)d_in[24];
  const float* W2  = (const float*)d_in[25];
  const float* b2  = (const float*)d_in[26];
  float* out = (float*)d_out;

  char* wsb = (char*)d_ws;
  size_t off = 0;
  auto alloc = [&](size_t bytes)->char*{
    char* p = wsb + off; off += (bytes + 255) & ~(size_t)255; return p;
  };
  u16* Wad16   = (u16*)alloc((size_t)512*2048*2);
  u16* We16    = (u16*)alloc((size_t)256*512*2);
  u16* W1_16   = (u16*)alloc((size_t)256*512*2);
  u16* W2pk    = (u16*)alloc((size_t)1875*8*512*2);
  unsigned* Wd2 = (unsigned*)alloc((size_t)256*256*4);
  u16* Wg0pk   = (u16*)alloc((size_t)2048*1536*2);
  u16* W1ppk   = (u16*)alloc((size_t)32*128*512*2);
  float* bias0p = (float*)alloc(2048*4);
  float* bias1p = (float*)alloc(2048*4);
  u16* embs16  = (u16*)alloc((size_t)1024*512*2);
  u16* pre16   = (u16*)alloc((size_t)6272*512*2);
  u16* enc16   = (u16*)alloc((size_t)6272*512*2);
  u16* att1_16 = (u16*)alloc((size_t)6272*256*2);
  u16* xh0     = (u16*)alloc((size_t)2*32*1536*2);   // zeroed region start
  float* c0buf = (float*)alloc(32*512*4);
  float* c1buf = (float*)alloc(32*512*4);            // zeroed region end
  float* part1 = (float*)alloc((size_t)32*32*2048*4);
  u16* h1all16 = (u16*)alloc((size_t)1024*512*2);
  u16* hid16   = (u16*)alloc((size_t)1024*256*2);

  hipMemsetAsync(xh0, 0, 196608 + 65536 + 65536, stream);

  // prep: one merged launch
  k_prep<<<PREP_BLOCKS,256,0,stream>>>(Wad, We, W1, W2, Wd,
                                       W_ih0, W_hh0, W_ih1, W_hh1,
                                       b_ih0, b_hh0, b_ih1, b_hh1,
                                       emb, captions,
                                       Wad16, We16, W1_16, W2pk, Wd2,
                                       Wg0pk, W1ppk, bias0p, bias1p, embs16);

  // encoder: XCD-panel-swizzled GEMMs (grid = 8*NQ*13)
  k_gemmF<64,64,64,8><<<832,256,0,stream>>>(features, Wad16, bad, pre16, 6272, 512, 2048);
  k_ln1<<<6272,64,0,stream>>>(pre16, g_ad, b_ad, enc16);
  k_gemm<1,64,64,64,4><<<416,256,0,stream>>>(enc16, We16, be, att1_16, 6272, 256, 512);

  // recurrence: 2 launches/step
  u16* xb[2] = { xh0, xh0 + 32*1536 };
  for (int t = 0; t < T_; ++t){
    k_ly<<<32,1024,0,stream>>>(part1, bias1p, c1buf, h1all16, Wd2, bd,
                               att1_16, enc16, Wf, bfp, embs16, xb[t&1], t);
    k_lx<<<32,1024,0,stream>>>(xb[t&1], xb[1-(t&1)], Wg0pk, bias0p,
                               W1ppk, h1all16, c0buf, part1, t);
  }
  // final finish: h1(31) -> h1all
  k_ly<<<32,1024,0,stream>>>(part1, bias1p, c1buf, h1all16, Wd2, bd,
                             att1_16, enc16, Wf, bfp, embs16, xb[0], T_);

  // tail: fused W1+LN+relu, then register-resident packed-W2 head
  k_w1<<<32,1024,0,stream>>>(h1all16, W1_16, b1, g1, bb1, hid16);
  k_head<<<dim3(118,2),1024,0,stream>>>(hid16, W2pk, b2, out);
}

// Round 15
// 1332.992 us; speedup vs baseline: 1.1318x; 1.1318x over previous
//
#include <hip/hip_runtime.h>

#define B_ 32
#define P_ 196
#define T_ 32
#define E_ 512
#define H_ 512
#define A_ 256
#define V_ 30000
#define FEAT_ 2048

typedef unsigned short u16;
typedef __attribute__((ext_vector_type(8))) short bf16x8;
typedef __attribute__((ext_vector_type(4))) float fx4;

#define MFMA16 __builtin_amdgcn_mfma_f32_16x16x32_bf16

__device__ __forceinline__ u16 f2b(float f){
  unsigned u = __builtin_bit_cast(unsigned, f);
  u += 0x7FFFu + ((u >> 16) & 1u);
  return (u16)(u >> 16);
}
__device__ __forceinline__ float b2f(u16 h){
  unsigned u = ((unsigned)h) << 16;
  return __builtin_bit_cast(float, u);
}
__device__ __forceinline__ float sigm(float x){ return 1.f/(1.f + __expf(-x)); }

// ================= merged prep: all packs/converts/gather in ONE launch =================
#define PREP_BLOCKS 25398
__global__ void k_prep(const float* __restrict__ Wad, const float* __restrict__ We,
                       const float* __restrict__ W1f, const float* __restrict__ W2f,
                       const float* __restrict__ Wd,
                       const float* __restrict__ Wih0, const float* __restrict__ Whh0,
                       const float* __restrict__ Wih1, const float* __restrict__ Whh1,
                       const float* __restrict__ bih0, const float* __restrict__ bhh0,
                       const float* __restrict__ bih1, const float* __restrict__ bhh1,
                       const float* __restrict__ emb, const int* __restrict__ cap,
                       u16* __restrict__ Wad16, u16* __restrict__ We16,
                       u16* __restrict__ W1_16, u16* __restrict__ W2pk,
                       unsigned* __restrict__ Wd2, u16* __restrict__ Wg0pk,
                       u16* __restrict__ W1ppk, float* __restrict__ bias0p,
                       float* __restrict__ bias1p, u16* __restrict__ embs16){
  int bid = blockIdx.x, tid = threadIdx.x;
  if (bid < 12288){                                   // ---- pack_g0
    int eid = bid*256 + tid;
    int j = eid & 7, l = (eid >> 3) & 63, frag = eid >> 9;
    int ks = frag % 12; int rest = frag / 12;
    int kw = rest & 3, q = (rest >> 2) & 3, s = rest >> 4;
    int n = q*512 + s*16 + (l & 15);
    int k = kw*384 + ks*32 + ((l >> 4) << 3) + j;
    float v = (k < 1024) ? Wih0[(size_t)n*1024 + k] : Whh0[(size_t)n*512 + (k - 1024)];
    Wg0pk[eid] = f2b(v);
  } else if (bid < 20480){                            // ---- pack_w1p
    int eid = (bid-12288)*256 + tid;
    int j = eid & 7, l = (eid >> 3) & 63, f = eid >> 9;
    int nf = f & 127, s = f >> 7;
    int np = nf*16 + (l & 15);
    int k = ((l >> 4) << 3) + j;
    int orig = ((np >> 4) & 3)*512 + (np >> 6)*16 + (np & 15);
    float v = (k < 16) ? Wih1[(size_t)orig*512 + s*16 + k]
                       : Whh1[(size_t)orig*512 + s*16 + (k - 16)];
    W1ppk[eid] = f2b(v);
  } else if (bid < 24230){                            // ---- pack_w2
    int i = (bid-20480)*256 + tid;
    int l = i & 63, kc = (i >> 6) & 7, nf = i >> 9;
    int row = nf*16 + (l & 15);
    int col = kc*32 + (l >> 4)*8;
    const float4* s = (const float4*)(W2f + (size_t)row*256 + col);
    float4 a = s[0], b = s[1];
    ushort4* d = (ushort4*)(W2pk + (size_t)i*8);
    d[0] = make_ushort4(f2b(a.x), f2b(a.y), f2b(a.z), f2b(a.w));
    d[1] = make_ushort4(f2b(b.x), f2b(b.y), f2b(b.z), f2b(b.w));
  } else if (bid < 24742){                            // ---- convert Wad
    int i = (bid-24230)*256 + tid;
    const float4* s = (const float4*)Wad + (size_t)i*2;
    float4 a = s[0], b = s[1];
    ushort4* d = (ushort4*)Wad16 + (size_t)i*2;
    d[0] = make_ushort4(f2b(a.x), f2b(a.y), f2b(a.z), f2b(a.w));
    d[1] = make_ushort4(f2b(b.x), f2b(b.y), f2b(b.z), f2b(b.w));
  } else if (bid < 24806){                            // ---- convert We
    int i = (bid-24742)*256 + tid;
    const float4* s = (const float4*)We + (size_t)i*2;
    float4 a = s[0], b = s[1];
    ushort4* d = (ushort4*)We16 + (size_t)i*2;
    d[0] = make_ushort4(f2b(a.x), f2b(a.y), f2b(a.z), f2b(a.w));
    d[1] = make_ushort4(f2b(b.x), f2b(b.y), f2b(b.z), f2b(b.w));
  } else if (bid < 24870){                            // ---- convert W1
    int i = (bid-24806)*256 + tid;
    const float4* s = (const float4*)W1f + (size_t)i*2;
    float4 a = s[0], b = s[1];
    ushort4* d = (ushort4*)W1_16 + (size_t)i*2;
    d[0] = make_ushort4(f2b(a.x), f2b(a.y), f2b(a.z), f2b(a.w));
    d[1] = make_ushort4(f2b(b.x), f2b(b.y), f2b(b.z), f2b(b.w));
  } else if (bid < 25126){                            // ---- pack_wd2
    int i = (bid-24870)*256 + tid;
    int n = i & 255, kp = i >> 8;
    unsigned lo = f2b(Wd[n*512 + 2*kp]);
    unsigned hi = f2b(Wd[n*512 + 2*kp + 1]);
    Wd2[i] = lo | (hi << 16);
  } else if (bid < 25134){                            // ---- bias0
    int n = (bid-25126)*256 + tid;
    int c = n & 15, q = (n >> 4) & 3, s = n >> 6;
    int orig = q*512 + s*16 + c;
    bias0p[n] = bih0[orig] + bhh0[orig];
  } else if (bid < 25142){                            // ---- bias1
    int n = (bid-25134)*256 + tid;
    int c = n & 15, q = (n >> 4) & 3, s = n >> 6;
    int orig = q*512 + s*16 + c;
    bias1p[n] = bih1[orig] + bhh1[orig];
  } else {                                            // ---- gather (4 rows/block)
    int r = (bid-25142)*4 + (tid >> 6), l = tid & 63;
    int t = r >> 5, b = r & 31;
    int c = cap[b*T_ + t];
    const float4* s = (const float4*)(emb + (size_t)c*E_) + l*2;
    float4 a = s[0], bb = s[1];
    ushort4* d = (ushort4*)(embs16 + (size_t)r*E_) + l*2;
    d[0] = make_ushort4(f2b(a.x), f2b(a.y), f2b(a.z), f2b(a.w));
    d[1] = make_ushort4(f2b(bb.x), f2b(bb.y), f2b(bb.z), f2b(bb.w));
  }
}

// ============ encoder GEMMs with XCD-panel swizzle ============
template<int MODE, int BM, int BN, int KS, int NQ>
__launch_bounds__(256)
__global__ void k_gemm(const u16* __restrict__ A, const u16* __restrict__ W,
                       const float* __restrict__ bias, u16* __restrict__ outB,
                       int M, int N, int K){
  constexpr int NI = BN/32, MI = BM/32, SEGS = KS/8;
  __shared__ __align__(16) u16 As[BM][KS+8];
  __shared__ __align__(16) u16 Bs[BN][KS+8];
  int f = blockIdx.x;
  int p8 = f & 7; int rest = f >> 3;
  int q = rest % NQ; int pHigh = rest / NQ;
  int p = pHigh*8 + p8;
  if (p*BM >= M) return;
  int m0 = p*BM, n0 = q*BN;
  int tid = threadIdx.x;
  int l = tid & 63, w = tid >> 6;
  int wr = w >> 1, wc = w & 1;
  fx4 acc[MI][NI];
  #pragma unroll
  for (int i=0;i<MI;i++)
    #pragma unroll
    for (int j=0;j<NI;j++) acc[i][j] = (fx4){0.f,0.f,0.f,0.f};
  int lr = l & 15, lg = l >> 4;
  for (int k0 = 0; k0 < K; k0 += KS){
    #pragma unroll
    for (int it=0; it<BM*SEGS/256; ++it){
      int flat = it*256 + tid, rr = flat/SEGS, cs = (flat%SEGS)*8;
      *(uint4*)&As[rr][cs] = *(const uint4*)(A + (size_t)(m0+rr)*K + k0 + cs);
    }
    uint4 z = {0u,0u,0u,0u};
    #pragma unroll
    for (int it=0; it<BN*SEGS/256; ++it){
      int flat = it*256 + tid, rr = flat/SEGS, cs = (flat%SEGS)*8;
      int rb = n0 + rr;
      *(uint4*)&Bs[rr][cs] = (rb < N) ? *(const uint4*)(W + (size_t)rb*K + k0 + cs) : z;
    }
    __syncthreads();
    #pragma unroll
    for (int kk=0; kk<KS/32; ++kk){
      bf16x8 av[MI], bv[NI];
      #pragma unroll
      for (int mi=0; mi<MI; mi++) av[mi] = *(const bf16x8*)&As[wr*(BM/2) + mi*16 + lr][kk*32 + lg*8];
      #pragma unroll
      for (int ni=0; ni<NI; ni++) bv[ni] = *(const bf16x8*)&Bs[wc*(BN/2) + ni*16 + lr][kk*32 + lg*8];
      #pragma unroll
      for (int mi=0; mi<MI; mi++)
        #pragma unroll
        for (int ni=0; ni<NI; ni++)
          acc[mi][ni] = MFMA16(av[mi], bv[ni], acc[mi][ni], 0, 0, 0);
    }
    __syncthreads();
  }
  #pragma unroll
  for (int mi=0; mi<MI; mi++)
    #pragma unroll
    for (int ni=0; ni<NI; ni++){
      int col = n0 + wc*(BN/2) + ni*16 + lr;
      if (col >= N) continue;
      float bvs = bias[col];
      #pragma unroll
      for (int reg=0; reg<4; reg++){
        int rowm = m0 + wr*(BM/2) + mi*16 + lg*4 + reg;
        float v = acc[mi][ni][reg] + bvs;
        if (MODE == 0) v = fmaxf(v, 0.f);
        outB[(size_t)rowm*N + col] = f2b(v);
      }
    }
}

// adapter: A is f32 (convert while staging), relu -> bf16; XCD swizzle; KS=128
template<int BM, int BN, int KS, int NQ>
__launch_bounds__(256)
__global__ void k_gemmF(const float* __restrict__ A, const u16* __restrict__ W,
                        const float* __restrict__ bias, u16* __restrict__ outB,
                        int M, int N, int K){
  constexpr int NI = BN/32, MI = BM/32, SEGS = KS/8;
  __shared__ __align__(16) u16 As[BM][KS+8];
  __shared__ __align__(16) u16 Bs[BN][KS+8];
  int f = blockIdx.x;
  int p8 = f & 7; int rest = f >> 3;
  int q = rest % NQ; int pHigh = rest / NQ;
  int p = pHigh*8 + p8;
  if (p*BM >= M) return;
  int m0 = p*BM, n0 = q*BN;
  int tid = threadIdx.x;
  int l = tid & 63, w = tid >> 6;
  int wr = w >> 1, wc = w & 1;
  fx4 acc[MI][NI];
  #pragma unroll
  for (int i=0;i<MI;i++)
    #pragma unroll
    for (int j=0;j<NI;j++) acc[i][j] = (fx4){0.f,0.f,0.f,0.f};
  int lr = l & 15, lg = l >> 4;
  for (int k0 = 0; k0 < K; k0 += KS){
    #pragma unroll
    for (int it=0; it<BM*SEGS/256; ++it){
      int flat = it*256 + tid, rr = flat/SEGS, cs = (flat%SEGS)*8;
      const float4* s = (const float4*)(A + (size_t)(m0+rr)*K + k0 + cs);
      float4 a0 = s[0], a1 = s[1];
      *(ushort4*)&As[rr][cs]   = make_ushort4(f2b(a0.x), f2b(a0.y), f2b(a0.z), f2b(a0.w));
      *(ushort4*)&As[rr][cs+4] = make_ushort4(f2b(a1.x), f2b(a1.y), f2b(a1.z), f2b(a1.w));
    }
    #pragma unroll
    for (int it=0; it<BN*SEGS/256; ++it){
      int flat = it*256 + tid, rr = flat/SEGS, cs = (flat%SEGS)*8;
      *(uint4*)&Bs[rr][cs] = *(const uint4*)(W + (size_t)(n0+rr)*K + k0 + cs);
    }
    __syncthreads();
    #pragma unroll
    for (int kk=0; kk<KS/32; ++kk){
      bf16x8 av[MI], bv[NI];
      #pragma unroll
      for (int mi=0; mi<MI; mi++) av[mi] = *(const bf16x8*)&As[wr*(BM/2) + mi*16 + lr][kk*32 + lg*8];
      #pragma unroll
      for (int ni=0; ni<NI; ni++) bv[ni] = *(const bf16x8*)&Bs[wc*(BN/2) + ni*16 + lr][kk*32 + lg*8];
      #pragma unroll
      for (int mi=0; mi<MI; mi++)
        #pragma unroll
        for (int ni=0; ni<NI; ni++)
          acc[mi][ni] = MFMA16(av[mi], bv[ni], acc[mi][ni], 0, 0, 0);
    }
    __syncthreads();
  }
  #pragma unroll
  for (int mi=0; mi<MI; mi++)
    #pragma unroll
    for (int ni=0; ni<NI; ni++){
      int col = n0 + wc*(BN/2) + ni*16 + lr;
      float bvs = bias[col];
      #pragma unroll
      for (int reg=0; reg<4; reg++){
        int rowm = m0 + wr*(BM/2) + mi*16 + lg*4 + reg;
        float v = fmaxf(acc[mi][ni][reg] + bvs, 0.f);
        outB[(size_t)rowm*N + col] = f2b(v);
      }
    }
}

// ---------------- LayerNorm over 512 (bf16 in/out) ----------------
__global__ void k_ln1(const u16* __restrict__ pre, const float* __restrict__ g,
                      const float* __restrict__ bt, u16* __restrict__ enc){
  int row = blockIdx.x; int l = threadIdx.x;
  bf16x8 vv = *(const bf16x8*)(pre + (size_t)row*E_ + l*8);
  float x[8]; float s = 0.f;
  #pragma unroll
  for (int i=0;i<8;i++){ x[i] = b2f((u16)vv[i]); s += x[i]; }
  #pragma unroll
  for (int off=32; off; off>>=1) s += __shfl_xor(s, off, 64);
  float mean = s * (1.f/512.f);
  float vs = 0.f;
  #pragma unroll
  for (int i=0;i<8;i++){ float d = x[i]-mean; vs += d*d; }
  #pragma unroll
  for (int off=32; off; off>>=1) vs += __shfl_xor(vs, off, 64);
  float inv = rsqrtf(vs*(1.f/512.f) + 1e-5f);
  int c0 = l*8;
  u16 o[8];
  #pragma unroll
  for (int i=0;i<8;i++) o[i] = f2b((x[i]-mean)*inv*g[c0+i] + bt[c0+i]);
  ushort4* d = (ushort4*)(enc + (size_t)row*E_ + c0);
  d[0] = make_ushort4(o[0],o[1],o[2],o[3]);
  d[1] = make_ushort4(o[4],o[5],o[6],o[7]);
}

// ---------------- W1 GEMM + LN + relu -> hid[(u*32+b)*256] ----------------
__device__ __forceinline__ void w1ln_block(const u16* __restrict__ h1all,
    const u16* __restrict__ W1, const float* __restrict__ b1,
    const float* __restrict__ g1v, const float* __restrict__ bb1,
    u16* __restrict__ hid, int u, int tid, float* red2, float* mv){
  int l = tid & 63, w = tid >> 6, lr = l & 15, lg = l >> 4;
  fx4 acc[2] = {{0,0,0,0},{0,0,0,0}};
  for (int k0 = 0; k0 < 512; k0 += 32){
    bf16x8 bv  = *(const bf16x8*)(W1 + (size_t)(w*16+lr)*512 + k0 + lg*8);
    bf16x8 av0 = *(const bf16x8*)(h1all + ((size_t)lr*T_ + u)*512 + k0 + lg*8);
    bf16x8 av1 = *(const bf16x8*)(h1all + ((size_t)(16+lr)*T_ + u)*512 + k0 + lg*8);
    acc[0] = MFMA16(av0, bv, acc[0], 0,0,0);
    acc[1] = MFMA16(av1, bv, acc[1], 0,0,0);
  }
  int col = w*16 + lr;
  float bc = b1[col];
  float val[2][4], s1[2][4], s2[2][4];
  #pragma unroll
  for (int mi=0;mi<2;mi++)
    #pragma unroll
    for (int reg=0;reg<4;reg++){
      float v = acc[mi][reg] + bc;
      val[mi][reg] = v; s1[mi][reg] = v; s2[mi][reg] = v*v;
    }
  #pragma unroll
  for (int off=1; off<16; off<<=1){
    #pragma unroll
    for (int mi=0;mi<2;mi++)
      #pragma unroll
      for (int reg=0;reg<4;reg++){
        s1[mi][reg] += __shfl_xor(s1[mi][reg], off, 64);
        s2[mi][reg] += __shfl_xor(s2[mi][reg], off, 64);
      }
  }
  if (lr == 0){
    #pragma unroll
    for (int mi=0;mi<2;mi++)
      #pragma unroll
      for (int reg=0;reg<4;reg++){
        int row = mi*16 + lg*4 + reg;
        red2[(0*16 + w)*32 + row] = s1[mi][reg];
        red2[(16   + w)*32 + row] = s2[mi][reg];
      }
  }
  __syncthreads();
  if (tid < 64){
    int which = tid >> 5, row = tid & 31;
    float s = 0.f;
    #pragma unroll
    for (int ww=0; ww<16; ++ww) s += red2[(which*16 + ww)*32 + row];
    mv[which*32 + row] = s;
  }
  __syncthreads();
  #pragma unroll
  for (int mi=0;mi<2;mi++)
    #pragma unroll
    for (int reg=0;reg<4;reg++){
      int row = mi*16 + lg*4 + reg;
      float mean = mv[row] * (1.f/256.f);
      float var  = mv[32+row] * (1.f/256.f) - mean*mean;
      float inv  = rsqrtf(var + 1e-5f);
      float o = fmaxf((val[mi][reg]-mean)*inv*g1v[col] + bb1[col], 0.f);
      hid[((size_t)u*32 + row)*256 + col] = f2b(o);
    }
}

__launch_bounds__(1024)
__global__ void k_w1(const u16* __restrict__ h1all, const u16* __restrict__ W1_16,
                     const float* __restrict__ b1, const float* __restrict__ g1v,
                     const float* __restrict__ bb1, u16* __restrict__ hid16){
  __shared__ float red2[1024];
  __shared__ float mv[64];
  w1ln_block(h1all, W1_16, b1, g1v, bb1, hid16, blockIdx.x, threadIdx.x, red2, mv);
}

// ---------------- head: W2 frags in registers, loop u; full-line stores ----------------
__launch_bounds__(1024)
__global__ void k_head(const u16* __restrict__ hid, const u16* __restrict__ W2pk,
                       const float* __restrict__ b2, float* __restrict__ out){
  __shared__ __align__(16) union { u16 hA[32][264]; float Cs[32][260]; } S;
  int c = blockIdx.x, uh = blockIdx.y, tid = threadIdx.x;
  int l = tid & 63, w = tid >> 6, lr = l & 15, lg = l >> 4;
  int nf = c*16 + w;
  bool valid = nf < 1875;
  bf16x8 bw[8];
  if (valid){
    const u16* wp = W2pk + (size_t)nf*4096 + l*8;
    #pragma unroll
    for (int k0=0;k0<8;k0++) bw[k0] = *(const bf16x8*)(wp + k0*512);
  }
  int srow = tid >> 5, scc = (tid & 31)*8;
  int col0 = c*256 + scc;
  float bb[8];
  #pragma unroll
  for (int j=0;j<8;j++) bb[j] = (col0 + j < V_) ? b2[col0 + j] : 0.f;

  for (int ui=0; ui<16; ++ui){
    int u = uh*16 + ui;
    { int arow = tid >> 5, ak = (tid & 31)*8;
      *(uint4*)&S.hA[arow][ak] = *(const uint4*)(hid + ((size_t)u*32 + arow)*256 + ak); }
    __syncthreads();
    fx4 acc0 = {0,0,0,0}, acc1 = {0,0,0,0};
    if (valid){
      #pragma unroll
      for (int k0=0;k0<8;k0++){
        bf16x8 av0 = *(const bf16x8*)&S.hA[lr][k0*32 + lg*8];
        bf16x8 av1 = *(const bf16x8*)&S.hA[16+lr][k0*32 + lg*8];
        acc0 = MFMA16(av0, bw[k0], acc0, 0,0,0);
        acc1 = MFMA16(av1, bw[k0], acc1, 0,0,0);
      }
    }
    __syncthreads();
    #pragma unroll
    for (int reg=0; reg<4; ++reg){
      S.Cs[lg*4+reg][w*16+lr]    = acc0[reg];
      S.Cs[16+lg*4+reg][w*16+lr] = acc1[reg];
    }
    __syncthreads();
    if (col0 + 8 <= V_){
      float4 v0, v1;
      v0.x = fminf(fmaxf(S.Cs[srow][scc+0] + bb[0], -10.f), 10.f);
      v0.y = fminf(fmaxf(S.Cs[srow][scc+1] + bb[1], -10.f), 10.f);
      v0.z = fminf(fmaxf(S.Cs[srow][scc+2] + bb[2], -10.f), 10.f);
      v0.w = fminf(fmaxf(S.Cs[srow][scc+3] + bb[3], -10.f), 10.f);
      v1.x = fminf(fmaxf(S.Cs[srow][scc+4] + bb[4], -10.f), 10.f);
      v1.y = fminf(fmaxf(S.Cs[srow][scc+5] + bb[5], -10.f), 10.f);
      v1.z = fminf(fmaxf(S.Cs[srow][scc+6] + bb[6], -10.f), 10.f);
      v1.w = fminf(fmaxf(S.Cs[srow][scc+7] + bb[7], -10.f), 10.f);
      float* o = out + ((size_t)srow*T_ + u)*V_ + col0;
      *(float4*)o = v0; *(float4*)(o+4) = v1;
    }
    __syncthreads();
  }
}

// ---------------- LY (R8-proven verbatim) ----------------
__launch_bounds__(1024)
__global__ void k_ly(const float* __restrict__ part1, const float* __restrict__ bias1p,
                     float* __restrict__ c1buf, u16* __restrict__ h1all,
                     const unsigned* __restrict__ Wd2, const float* __restrict__ bd,
                     const u16* __restrict__ att1b, const u16* __restrict__ enc16,
                     const float* __restrict__ Wf, const float* __restrict__ bfp,
                     const u16* __restrict__ embs, u16* __restrict__ xh0cur, int t){
  int b = blockIdx.x, tid = threadIdx.x;
  int l = tid & 63, wid = tid >> 6;
  __shared__ float g1s[2048];
  __shared__ float h1s[512];
  __shared__ float a2p[4][256];
  __shared__ float a2[256], ev[256], red[8], wfv[256], bdv[256];
  __shared__ float cb[4][256][2];
  if (tid < 256){ wfv[tid] = Wf[tid]; bdv[tid] = bd[tid]; }
  float bf0 = bfp[0];

  if (t > 0){
    float acc0 = bias1p[tid], acc1 = bias1p[tid + 1024];
    #pragma unroll 4
    for (int s2=0; s2<32; ++s2){
      const float* pp = part1 + ((size_t)(s2*32 + b))*2048;
      acc0 += pp[tid];
      acc1 += pp[tid + 1024];
    }
    g1s[tid] = acc0; g1s[tid + 1024] = acc1;
    __syncthreads();
    if (tid < 512){
      int h = tid, s4 = h >> 4, c = h & 15, base = s4*64 + c;
      float gi = g1s[base], gf = g1s[base+16], gg = g1s[base+32], go = g1s[base+48];
      float cold = c1buf[b*512 + h];
      float cn = sigm(gf)*cold + sigm(gi)*tanhf(gg);
      c1buf[b*512 + h] = cn;
      float hn = sigm(go)*tanhf(cn);
      h1s[h] = hn;
      h1all[((size_t)b*T_ + (t-1))*512 + h] = f2b(hn);
    }
  } else {
    if (tid < 512) h1s[tid] = 0.f;
  }
  __syncthreads();
  if (t >= T_) return;

  {
    int n = tid & 255, kq = tid >> 8;
    float acc = 0.f;
    const unsigned* wp = Wd2 + (size_t)kq*64*256 + n;
    #pragma unroll 8
    for (int kp2 = 0; kp2 < 64; ++kp2){
      unsigned wv = wp[(size_t)kp2*256];
      int k0 = (kq*64 + kp2)*2;
      acc += h1s[k0]   * b2f((u16)(wv & 0xFFFFu))
           + h1s[k0+1] * b2f((u16)(wv >> 16));
    }
    a2p[kq][n] = acc;
  }
  __syncthreads();
  if (tid < 256) a2[tid] = a2p[0][tid] + a2p[1][tid] + a2p[2][tid] + a2p[3][tid] + bdv[tid];
  __syncthreads();
  for (int pi = 0; pi < 13; ++pi){
    int p = pi*16 + wid;
    if (p < P_){
      ushort4 av4 = *(const ushort4*)(att1b + (size_t)(b*P_ + p)*A_ + l*4);
      int j0 = l*4;
      float sum = fmaxf(b2f(av4.x)+a2[j0],  0.f)*wfv[j0]
                + fmaxf(b2f(av4.y)+a2[j0+1],0.f)*wfv[j0+1]
                + fmaxf(b2f(av4.z)+a2[j0+2],0.f)*wfv[j0+2]
                + fmaxf(b2f(av4.w)+a2[j0+3],0.f)*wfv[j0+3];
      #pragma unroll
      for (int off=32; off; off>>=1) sum += __shfl_xor(sum, off, 64);
      if (l == 0) ev[p] = sum + bf0;
    }
  }
  __syncthreads();
  if (tid < 256){
    float v = (tid < P_) ? ev[tid] : -1e30f;
    float m = v;
    #pragma unroll
    for (int off=32; off; off>>=1) m = fmaxf(m, __shfl_xor(m, off, 64));
    if (l == 0) red[wid] = m;
  }
  __syncthreads();
  float mg = fmaxf(fmaxf(red[0],red[1]), fmaxf(red[2],red[3]));
  if (tid < 256){
    float ex = (tid < P_) ? __expf(ev[tid] - mg) : 0.f;
    float ss = ex;
    #pragma unroll
    for (int off=32; off; off>>=1) ss += __shfl_xor(ss, off, 64);
    if (l == 0) red[4+wid] = ss;
    ev[tid] = ex;
  }
  __syncthreads();
  float inv = 1.f/(red[4]+red[5]+red[6]+red[7]);
  {
    int j = tid & 255, pq = tid >> 8;
    float A0 = 0.f, A1 = 0.f;
    const unsigned* ep = (const unsigned*)enc16 + ((size_t)b*P_ + pq*49)*256 + j;
    #pragma unroll 7
    for (int pi = 0; pi < 49; ++pi){
      unsigned vv = ep[(size_t)pi*256];
      float al = ev[pq*49 + pi];
      A0 += al * b2f((u16)(vv & 0xFFFFu));
      A1 += al * b2f((u16)(vv >> 16));
    }
    cb[pq][j][0] = A0; cb[pq][j][1] = A1;
  }
  __syncthreads();
  if (tid < 256){
    float c0 = (cb[0][tid][0]+cb[1][tid][0]+cb[2][tid][0]+cb[3][tid][0]) * inv;
    float c1 = (cb[0][tid][1]+cb[1][tid][1]+cb[2][tid][1]+cb[3][tid][1]) * inv;
    unsigned o = (unsigned)f2b(c0) | (((unsigned)f2b(c1)) << 16);
    *((unsigned*)(xh0cur + (size_t)b*1536 + 512) + tid) = o;
    ((unsigned*)(xh0cur + (size_t)b*1536))[tid] =
        ((const unsigned*)(embs + (size_t)(t*32+b)*E_))[tid];
  }
}

// ---------------- LX (R8/R13-proven verbatim) ----------------
__launch_bounds__(1024)
__global__ void k_lx(const u16* __restrict__ xh0cur, u16* __restrict__ xh0nxt,
                     const u16* __restrict__ Wg0pk, const float* __restrict__ bias0p,
                     const u16* __restrict__ W1ppk, const u16* __restrict__ h1all,
                     float* __restrict__ c0buf, float* __restrict__ part1, int t){
  __shared__ float part[16][32][16];
  __shared__ float gsum[4][32][16];
  __shared__ __align__(16) u16 As[32][40];
  int tid = threadIdx.x, s = blockIdx.x;
  int l = tid & 63, kw = tid >> 6, lr = l & 15, lg = l >> 4;

  bf16x8 a[2][3];
  #pragma unroll
  for (int mi=0;mi<2;mi++)
    #pragma unroll
    for (int ks=0;ks<3;ks++)
      a[mi][ks] = *(const bf16x8*)(xh0cur + (size_t)(mi*16+lr)*1536 + kw*96 + ks*32 + lg*8);
  for (int q=0;q<4;q++){
    fx4 acc0 = (fx4){0,0,0,0}, acc1 = (fx4){0,0,0,0};
    const u16* wp = Wg0pk + (size_t)(((s*4+q)*4 + (kw>>2))*12 + (kw&3)*3)*512 + l*8;
    #pragma unroll
    for (int ks=0;ks<3;ks++){
      bf16x8 bf8 = *(const bf16x8*)(wp + ks*512);
      acc0 = MFMA16(a[0][ks], bf8, acc0, 0,0,0);
      acc1 = MFMA16(a[1][ks], bf8, acc1, 0,0,0);
    }
    #pragma unroll
    for (int reg=0;reg<4;reg++){
      part[kw][lg*4+reg][lr]    = acc0[reg];
      part[kw][16+lg*4+reg][lr] = acc1[reg];
    }
    __syncthreads();
    if (tid < 512){
      int bb = tid >> 4, c = tid & 15;
      float g = bias0p[s*64 + q*16 + c];
      #pragma unroll
      for (int kw2=0; kw2<16; ++kw2) g += part[kw2][bb][c];
      gsum[q][bb][c] = g;
    }
    __syncthreads();
  }
  if (tid < 256){
    int bb = tid >> 3, kk = (tid & 7)*2;
    unsigned hv = 0;
    if (t > 0) hv = *(const unsigned*)(h1all + ((size_t)bb*T_ + (t-1))*512 + s*16 + kk);
    *(unsigned*)&As[bb][16+kk] = hv;
  }
  if (tid < 512){
    int bb = tid >> 4, c = tid & 15;
    int h = s*16 + c;
    float gi = gsum[0][bb][c], gf = gsum[1][bb][c], gg = gsum[2][bb][c], go = gsum[3][bb][c];
    float cold = c0buf[bb*512 + h];
    float cn = sigm(gf)*cold + sigm(gi)*tanhf(gg);
    c0buf[bb*512 + h] = cn;
    u16 hb = f2b(sigm(go)*tanhf(cn));
    xh0nxt[(size_t)bb*1536 + 1024 + h] = hb;
    As[bb][c] = hb;
  }
  __syncthreads();
  bf16x8 pa0 = *(const bf16x8*)&As[lr][lg*8];
  bf16x8 pa1 = *(const bf16x8*)&As[16+lr][lg*8];
  #pragma unroll 2
  for (int i=0;i<8;i++){
    int nf = kw*8 + i;
    bf16x8 bf8 = *(const bf16x8*)(W1ppk + (size_t)(s*128 + nf)*512 + l*8);
    fx4 A0 = MFMA16(pa0, bf8, (fx4){0,0,0,0}, 0,0,0);
    fx4 A1 = MFMA16(pa1, bf8, (fx4){0,0,0,0}, 0,0,0);
    float* o = part1 + ((size_t)s*32)*2048 + nf*16 + lr;
    #pragma unroll
    for (int reg=0;reg<4;reg++){
      o[(size_t)(lg*4+reg)*2048]    = A0[reg];
      o[(size_t)(16+lg*4+reg)*2048] = A1[reg];
    }
  }
}

extern "C" void kernel_launch(void* const* d_in, const int* in_sizes, int n_in,
                              void* d_out, int out_size, void* d_ws, size_t ws_size,
                              hipStream_t stream){
  (void)in_sizes; (void)n_in; (void)out_size; (void)ws_size;
  const float* features = (const float*)d_in[0];
  const int*   captions = (const int*)d_in[1];
  const float* Wad  = (const float*)d_in[2];
  const float* bad  = (const float*)d_in[3];
  const float* g_ad = (const float*)d_in[4];
  const float* b_ad = (const float*)d_in[5];
  const float* We   = (const float*)d_in[6];
  const float* be   = (const float*)d_in[7];
  const float* Wd   = (const float*)d_in[8];
  const float* bd   = (const float*)d_in[9];
  const float* Wf   = (const float*)d_in[10];
  const float* bfp  = (const float*)d_in[11];
  const float* emb  = (const float*)d_in[12];
  const float* W_ih0 = (const float*)d_in[13];
  const float* W_hh0 = (const float*)d_in[14];
  const float* b_ih0 = (const float*)d_in[15];
  const float* b_hh0 = (const float*)d_in[16];
  const float* W_ih1 = (const float*)d_in[17];
  const float* W_hh1 = (const float*)d_in[18];
  const float* b_ih1 = (const float*)d_in[19];
  const float* b_hh1 = (const float*)d_in[20];
  const float* W1  = (const float*)d_in[21];
  const float* b1  = (const float*)d_in[22];
  const float* g1  = (const float*)d_in[23];
  const float* bb1 = (const float*)d_in[24];
  const float* W2  = (const float*)d_in[25];
  const float* b2  = (const float*)d_in[26];
  float* out = (float*)d_out;

  char* wsb = (char*)d_ws;
  size_t off = 0;
  auto alloc = [&](size_t bytes)->char*{
    char* p = wsb + off; off += (bytes + 255) & ~(size_t)255; return p;
  };
  u16* Wad16   = (u16*)alloc((size_t)512*2048*2);
  u16* We16    = (u16*)alloc((size_t)256*512*2);
  u16* W1_16   = (u16*)alloc((size_t)256*512*2);
  u16* W2pk    = (u16*)alloc((size_t)1875*8*512*2);
  unsigned* Wd2 = (unsigned*)alloc((size_t)256*256*4);
  u16* Wg0pk   = (u16*)alloc((size_t)2048*1536*2);
  u16* W1ppk   = (u16*)alloc((size_t)32*128*512*2);
  float* bias0p = (float*)alloc(2048*4);
  float* bias1p = (float*)alloc(2048*4);
  u16* embs16  = (u16*)alloc((size_t)1024*512*2);
  u16* pre16   = (u16*)alloc((size_t)6272*512*2);
  u16* enc16   = (u16*)alloc((size_t)6272*512*2);
  u16* att1_16 = (u16*)alloc((size_t)6272*256*2);
  u16* xh0     = (u16*)alloc((size_t)2*32*1536*2);   // zeroed region start
  float* c0buf = (float*)alloc(32*512*4);
  float* c1buf = (float*)alloc(32*512*4);            // zeroed region end
  float* part1 = (float*)alloc((size_t)32*32*2048*4);
  u16* h1all16 = (u16*)alloc((size_t)1024*512*2);
  u16* hid16   = (u16*)alloc((size_t)1024*256*2);

  hipMemsetAsync(xh0, 0, 196608 + 65536 + 65536, stream);

  // prep: one merged launch
  k_prep<<<PREP_BLOCKS,256,0,stream>>>(Wad, We, W1, W2, Wd,
                                       W_ih0, W_hh0, W_ih1, W_hh1,
                                       b_ih0, b_hh0, b_ih1, b_hh1,
                                       emb, captions,
                                       Wad16, We16, W1_16, W2pk, Wd2,
                                       Wg0pk, W1ppk, bias0p, bias1p, embs16);

  // encoder: XCD-panel-swizzled GEMMs; adapter KS=128 (half the barriers)
  k_gemmF<64,64,128,8><<<832,256,0,stream>>>(features, Wad16, bad, pre16, 6272, 512, 2048);
  k_ln1<<<6272,64,0,stream>>>(pre16, g_ad, b_ad, enc16);
  k_gemm<1,64,64,64,4><<<416,256,0,stream>>>(enc16, We16, be, att1_16, 6272, 256, 512);

  // recurrence: 2 launches/step (R8/R13-proven kernels)
  u16* xb[2] = { xh0, xh0 + 32*1536 };
  for (int t = 0; t < T_; ++t){
    k_ly<<<32,1024,0,stream>>>(part1, bias1p, c1buf, h1all16, Wd2, bd,
                               att1_16, enc16, Wf, bfp, embs16, xb[t&1], t);
    k_lx<<<32,1024,0,stream>>>(xb[t&1], xb[1-(t&1)], Wg0pk, bias0p,
                               W1ppk, h1all16, c0buf, part1, t);
  }
  // final finish: h1(31) -> h1all
  k_ly<<<32,1024,0,stream>>>(part1, bias1p, c1buf, h1all16, Wd2, bd,
                             att1_16, enc16, Wf, bfp, embs16, xb[0], T_);

  // tail: fused W1+LN+relu, then register-resident packed-W2 head
  k_w1<<<32,1024,0,stream>>>(h1all16, W1_16, b1, g1, bb1, hid16);
  k_head<<<dim3(118,2),1024,0,stream>>>(hid16, W2pk, b2, out);
}

// Round 16
// 1243.662 us; speedup vs baseline: 1.2131x; 1.0718x over previous
//
#include <hip/hip_runtime.h>

#define B_ 32
#define P_ 196
#define T_ 32
#define E_ 512
#define H_ 512
#define A_ 256
#define V_ 30000
#define FEAT_ 2048

typedef unsigned short u16;
typedef __attribute__((ext_vector_type(8))) short bf16x8;
typedef __attribute__((ext_vector_type(4))) float fx4;

#define MFMA16 __builtin_amdgcn_mfma_f32_16x16x32_bf16

__device__ __forceinline__ u16 f2b(float f){
  unsigned u = __builtin_bit_cast(unsigned, f);
  u += 0x7FFFu + ((u >> 16) & 1u);
  return (u16)(u >> 16);
}
__device__ __forceinline__ float b2f(u16 h){
  unsigned u = ((unsigned)h) << 16;
  return __builtin_bit_cast(float, u);
}
__device__ __forceinline__ float sigm(float x){ return 1.f/(1.f + __expf(-x)); }

// ================= merged prep: all packs/converts/gather + features in ONE launch =================
// [0,12288) pack_g0 | [12288,20480) pack_w1p | [20480,24230) pack_w2 | [24230,24742) cvt Wad
// [24742,24806) cvt We | [24806,24870) cvt W1 | [24870,25126) pack_wd2 | [25126,25134) bias0
// [25134,25142) bias1 | [25142,25398) gather | [25398,31670) cvt features
#define PREP_BLOCKS 31670
__global__ void k_prep(const float* __restrict__ Wad, const float* __restrict__ We,
                       const float* __restrict__ W1f, const float* __restrict__ W2f,
                       const float* __restrict__ Wd,
                       const float* __restrict__ Wih0, const float* __restrict__ Whh0,
                       const float* __restrict__ Wih1, const float* __restrict__ Whh1,
                       const float* __restrict__ bih0, const float* __restrict__ bhh0,
                       const float* __restrict__ bih1, const float* __restrict__ bhh1,
                       const float* __restrict__ emb, const int* __restrict__ cap,
                       const float* __restrict__ feat,
                       u16* __restrict__ Wad16, u16* __restrict__ We16,
                       u16* __restrict__ W1_16, u16* __restrict__ W2pk,
                       unsigned* __restrict__ Wd2, u16* __restrict__ Wg0pk,
                       u16* __restrict__ W1ppk, float* __restrict__ bias0p,
                       float* __restrict__ bias1p, u16* __restrict__ embs16,
                       u16* __restrict__ fb16){
  int bid = blockIdx.x, tid = threadIdx.x;
  if (bid < 12288){
    int eid = bid*256 + tid;
    int j = eid & 7, l = (eid >> 3) & 63, frag = eid >> 9;
    int ks = frag % 12; int rest = frag / 12;
    int kw = rest & 3, q = (rest >> 2) & 3, s = rest >> 4;
    int n = q*512 + s*16 + (l & 15);
    int k = kw*384 + ks*32 + ((l >> 4) << 3) + j;
    float v = (k < 1024) ? Wih0[(size_t)n*1024 + k] : Whh0[(size_t)n*512 + (k - 1024)];
    Wg0pk[eid] = f2b(v);
  } else if (bid < 20480){
    int eid = (bid-12288)*256 + tid;
    int j = eid & 7, l = (eid >> 3) & 63, f = eid >> 9;
    int nf = f & 127, s = f >> 7;
    int np = nf*16 + (l & 15);
    int k = ((l >> 4) << 3) + j;
    int orig = ((np >> 4) & 3)*512 + (np >> 6)*16 + (np & 15);
    float v = (k < 16) ? Wih1[(size_t)orig*512 + s*16 + k]
                       : Whh1[(size_t)orig*512 + s*16 + (k - 16)];
    W1ppk[eid] = f2b(v);
  } else if (bid < 24230){
    int i = (bid-20480)*256 + tid;
    int l = i & 63, kc = (i >> 6) & 7, nf = i >> 9;
    int row = nf*16 + (l & 15);
    int col = kc*32 + (l >> 4)*8;
    const float4* s = (const float4*)(W2f + (size_t)row*256 + col);
    float4 a = s[0], b = s[1];
    ushort4* d = (ushort4*)(W2pk + (size_t)i*8);
    d[0] = make_ushort4(f2b(a.x), f2b(a.y), f2b(a.z), f2b(a.w));
    d[1] = make_ushort4(f2b(b.x), f2b(b.y), f2b(b.z), f2b(b.w));
  } else if (bid < 24742){
    int i = (bid-24230)*256 + tid;
    const float4* s = (const float4*)Wad + (size_t)i*2;
    float4 a = s[0], b = s[1];
    ushort4* d = (ushort4*)Wad16 + (size_t)i*2;
    d[0] = make_ushort4(f2b(a.x), f2b(a.y), f2b(a.z), f2b(a.w));
    d[1] = make_ushort4(f2b(b.x), f2b(b.y), f2b(b.z), f2b(b.w));
  } else if (bid < 24806){
    int i = (bid-24742)*256 + tid;
    const float4* s = (const float4*)We + (size_t)i*2;
    float4 a = s[0], b = s[1];
    ushort4* d = (ushort4*)We16 + (size_t)i*2;
    d[0] = make_ushort4(f2b(a.x), f2b(a.y), f2b(a.z), f2b(a.w));
    d[1] = make_ushort4(f2b(b.x), f2b(b.y), f2b(b.z), f2b(b.w));
  } else if (bid < 24870){
    int i = (bid-24806)*256 + tid;
    const float4* s = (const float4*)W1f + (size_t)i*2;
    float4 a = s[0], b = s[1];
    ushort4* d = (ushort4*)W1_16 + (size_t)i*2;
    d[0] = make_ushort4(f2b(a.x), f2b(a.y), f2b(a.z), f2b(a.w));
    d[1] = make_ushort4(f2b(b.x), f2b(b.y), f2b(b.z), f2b(b.w));
  } else if (bid < 25126){
    int i = (bid-24870)*256 + tid;
    int n = i & 255, kp = i >> 8;
    unsigned lo = f2b(Wd[n*512 + 2*kp]);
    unsigned hi = f2b(Wd[n*512 + 2*kp + 1]);
    Wd2[i] = lo | (hi << 16);
  } else if (bid < 25134){
    int n = (bid-25126)*256 + tid;
    int c = n & 15, q = (n >> 4) & 3, s = n >> 6;
    int orig = q*512 + s*16 + c;
    bias0p[n] = bih0[orig] + bhh0[orig];
  } else if (bid < 25142){
    int n = (bid-25134)*256 + tid;
    int c = n & 15, q = (n >> 4) & 3, s = n >> 6;
    int orig = q*512 + s*16 + c;
    bias1p[n] = bih1[orig] + bhh1[orig];
  } else if (bid < 25398){
    int r = (bid-25142)*4 + (tid >> 6), l = tid & 63;
    int t = r >> 5, b = r & 31;
    int c = cap[b*T_ + t];
    const float4* s = (const float4*)(emb + (size_t)c*E_) + l*2;
    float4 a = s[0], bb = s[1];
    ushort4* d = (ushort4*)(embs16 + (size_t)r*E_) + l*2;
    d[0] = make_ushort4(f2b(a.x), f2b(a.y), f2b(a.z), f2b(a.w));
    d[1] = make_ushort4(f2b(bb.x), f2b(bb.y), f2b(bb.z), f2b(bb.w));
  } else {                                            // ---- convert features (bf16)
    int i = (bid-25398)*256 + tid;
    const float4* s = (const float4*)feat + (size_t)i*2;
    float4 a = s[0], b = s[1];
    ushort4* d = (ushort4*)fb16 + (size_t)i*2;
    d[0] = make_ushort4(f2b(a.x), f2b(a.y), f2b(a.z), f2b(a.w));
    d[1] = make_ushort4(f2b(b.x), f2b(b.y), f2b(b.z), f2b(b.w));
  }
}

// ============ encoder GEMMs with XCD-panel swizzle ============
template<int MODE, int BM, int BN, int KS, int NQ>
__launch_bounds__(256)
__global__ void k_gemm(const u16* __restrict__ A, const u16* __restrict__ W,
                       const float* __restrict__ bias, u16* __restrict__ outB,
                       int M, int N, int K){
  constexpr int NI = BN/32, MI = BM/32, SEGS = KS/8;
  __shared__ __align__(16) u16 As[BM][KS+8];
  __shared__ __align__(16) u16 Bs[BN][KS+8];
  int f = blockIdx.x;
  int p8 = f & 7; int rest = f >> 3;
  int q = rest % NQ; int pHigh = rest / NQ;
  int p = pHigh*8 + p8;
  if (p*BM >= M) return;
  int m0 = p*BM, n0 = q*BN;
  int tid = threadIdx.x;
  int l = tid & 63, w = tid >> 6;
  int wr = w >> 1, wc = w & 1;
  fx4 acc[MI][NI];
  #pragma unroll
  for (int i=0;i<MI;i++)
    #pragma unroll
    for (int j=0;j<NI;j++) acc[i][j] = (fx4){0.f,0.f,0.f,0.f};
  int lr = l & 15, lg = l >> 4;
  for (int k0 = 0; k0 < K; k0 += KS){
    #pragma unroll
    for (int it=0; it<BM*SEGS/256; ++it){
      int flat = it*256 + tid, rr = flat/SEGS, cs = (flat%SEGS)*8;
      *(uint4*)&As[rr][cs] = *(const uint4*)(A + (size_t)(m0+rr)*K + k0 + cs);
    }
    uint4 z = {0u,0u,0u,0u};
    #pragma unroll
    for (int it=0; it<BN*SEGS/256; ++it){
      int flat = it*256 + tid, rr = flat/SEGS, cs = (flat%SEGS)*8;
      int rb = n0 + rr;
      *(uint4*)&Bs[rr][cs] = (rb < N) ? *(const uint4*)(W + (size_t)rb*K + k0 + cs) : z;
    }
    __syncthreads();
    #pragma unroll
    for (int kk=0; kk<KS/32; ++kk){
      bf16x8 av[MI], bv[NI];
      #pragma unroll
      for (int mi=0; mi<MI; mi++) av[mi] = *(const bf16x8*)&As[wr*(BM/2) + mi*16 + lr][kk*32 + lg*8];
      #pragma unroll
      for (int ni=0; ni<NI; ni++) bv[ni] = *(const bf16x8*)&Bs[wc*(BN/2) + ni*16 + lr][kk*32 + lg*8];
      #pragma unroll
      for (int mi=0; mi<MI; mi++)
        #pragma unroll
        for (int ni=0; ni<NI; ni++)
          acc[mi][ni] = MFMA16(av[mi], bv[ni], acc[mi][ni], 0, 0, 0);
    }
    __syncthreads();
  }
  #pragma unroll
  for (int mi=0; mi<MI; mi++)
    #pragma unroll
    for (int ni=0; ni<NI; ni++){
      int col = n0 + wc*(BN/2) + ni*16 + lr;
      if (col >= N) continue;
      float bvs = bias[col];
      #pragma unroll
      for (int reg=0; reg<4; reg++){
        int rowm = m0 + wr*(BM/2) + mi*16 + lg*4 + reg;
        float v = acc[mi][ni][reg] + bvs;
        if (MODE == 0) v = fmaxf(v, 0.f);
        outB[(size_t)rowm*N + col] = f2b(v);
      }
    }
}

// ---------------- LayerNorm over 512 (bf16 in/out) ----------------
__global__ void k_ln1(const u16* __restrict__ pre, const float* __restrict__ g,
                      const float* __restrict__ bt, u16* __restrict__ enc){
  int row = blockIdx.x; int l = threadIdx.x;
  bf16x8 vv = *(const bf16x8*)(pre + (size_t)row*E_ + l*8);
  float x[8]; float s = 0.f;
  #pragma unroll
  for (int i=0;i<8;i++){ x[i] = b2f((u16)vv[i]); s += x[i]; }
  #pragma unroll
  for (int off=32; off; off>>=1) s += __shfl_xor(s, off, 64);
  float mean = s * (1.f/512.f);
  float vs = 0.f;
  #pragma unroll
  for (int i=0;i<8;i++){ float d = x[i]-mean; vs += d*d; }
  #pragma unroll
  for (int off=32; off; off>>=1) vs += __shfl_xor(vs, off, 64);
  float inv = rsqrtf(vs*(1.f/512.f) + 1e-5f);
  int c0 = l*8;
  u16 o[8];
  #pragma unroll
  for (int i=0;i<8;i++) o[i] = f2b((x[i]-mean)*inv*g[c0+i] + bt[c0+i]);
  ushort4* d = (ushort4*)(enc + (size_t)row*E_ + c0);
  d[0] = make_ushort4(o[0],o[1],o[2],o[3]);
  d[1] = make_ushort4(o[4],o[5],o[6],o[7]);
}

// ---------------- W1 GEMM + LN + relu -> hid[(u*32+b)*256] ----------------
__device__ __forceinline__ void w1ln_block(const u16* __restrict__ h1all,
    const u16* __restrict__ W1, const float* __restrict__ b1,
    const float* __restrict__ g1v, const float* __restrict__ bb1,
    u16* __restrict__ hid, int u, int tid, float* red2, float* mv){
  int l = tid & 63, w = tid >> 6, lr = l & 15, lg = l >> 4;
  fx4 acc[2] = {{0,0,0,0},{0,0,0,0}};
  for (int k0 = 0; k0 < 512; k0 += 32){
    bf16x8 bv  = *(const bf16x8*)(W1 + (size_t)(w*16+lr)*512 + k0 + lg*8);
    bf16x8 av0 = *(const bf16x8*)(h1all + ((size_t)lr*T_ + u)*512 + k0 + lg*8);
    bf16x8 av1 = *(const bf16x8*)(h1all + ((size_t)(16+lr)*T_ + u)*512 + k0 + lg*8);
    acc[0] = MFMA16(av0, bv, acc[0], 0,0,0);
    acc[1] = MFMA16(av1, bv, acc[1], 0,0,0);
  }
  int col = w*16 + lr;
  float bc = b1[col];
  float val[2][4], s1[2][4], s2[2][4];
  #pragma unroll
  for (int mi=0;mi<2;mi++)
    #pragma unroll
    for (int reg=0;reg<4;reg++){
      float v = acc[mi][reg] + bc;
      val[mi][reg] = v; s1[mi][reg] = v; s2[mi][reg] = v*v;
    }
  #pragma unroll
  for (int off=1; off<16; off<<=1){
    #pragma unroll
    for (int mi=0;mi<2;mi++)
      #pragma unroll
      for (int reg=0;reg<4;reg++){
        s1[mi][reg] += __shfl_xor(s1[mi][reg], off, 64);
        s2[mi][reg] += __shfl_xor(s2[mi][reg], off, 64);
      }
  }
  if (lr == 0){
    #pragma unroll
    for (int mi=0;mi<2;mi++)
      #pragma unroll
      for (int reg=0;reg<4;reg++){
        int row = mi*16 + lg*4 + reg;
        red2[(0*16 + w)*32 + row] = s1[mi][reg];
        red2[(16   + w)*32 + row] = s2[mi][reg];
      }
  }
  __syncthreads();
  if (tid < 64){
    int which = tid >> 5, row = tid & 31;
    float s = 0.f;
    #pragma unroll
    for (int ww=0; ww<16; ++ww) s += red2[(which*16 + ww)*32 + row];
    mv[which*32 + row] = s;
  }
  __syncthreads();
  #pragma unroll
  for (int mi=0;mi<2;mi++)
    #pragma unroll
    for (int reg=0;reg<4;reg++){
      int row = mi*16 + lg*4 + reg;
      float mean = mv[row] * (1.f/256.f);
      float var  = mv[32+row] * (1.f/256.f) - mean*mean;
      float inv  = rsqrtf(var + 1e-5f);
      float o = fmaxf((val[mi][reg]-mean)*inv*g1v[col] + bb1[col], 0.f);
      hid[((size_t)u*32 + row)*256 + col] = f2b(o);
    }
}

__launch_bounds__(1024)
__global__ void k_w1(const u16* __restrict__ h1all, const u16* __restrict__ W1_16,
                     const float* __restrict__ b1, const float* __restrict__ g1v,
                     const float* __restrict__ bb1, u16* __restrict__ hid16){
  __shared__ float red2[1024];
  __shared__ float mv[64];
  w1ln_block(h1all, W1_16, b1, g1v, bb1, hid16, blockIdx.x, threadIdx.x, red2, mv);
}

// ---------------- head: W2 frags in registers, loop u; full-line stores ----------------
__launch_bounds__(1024)
__global__ void k_head(const u16* __restrict__ hid, const u16* __restrict__ W2pk,
                       const float* __restrict__ b2, float* __restrict__ out){
  __shared__ __align__(16) union { u16 hA[32][264]; float Cs[32][260]; } S;
  int c = blockIdx.x, uh = blockIdx.y, tid = threadIdx.x;
  int l = tid & 63, w = tid >> 6, lr = l & 15, lg = l >> 4;
  int nf = c*16 + w;
  bool valid = nf < 1875;
  bf16x8 bw[8];
  if (valid){
    const u16* wp = W2pk + (size_t)nf*4096 + l*8;
    #pragma unroll
    for (int k0=0;k0<8;k0++) bw[k0] = *(const bf16x8*)(wp + k0*512);
  }
  int srow = tid >> 5, scc = (tid & 31)*8;
  int col0 = c*256 + scc;
  float bb[8];
  #pragma unroll
  for (int j=0;j<8;j++) bb[j] = (col0 + j < V_) ? b2[col0 + j] : 0.f;

  for (int ui=0; ui<16; ++ui){
    int u = uh*16 + ui;
    { int arow = tid >> 5, ak = (tid & 31)*8;
      *(uint4*)&S.hA[arow][ak] = *(const uint4*)(hid + ((size_t)u*32 + arow)*256 + ak); }
    __syncthreads();
    fx4 acc0 = {0,0,0,0}, acc1 = {0,0,0,0};
    if (valid){
      #pragma unroll
      for (int k0=0;k0<8;k0++){
        bf16x8 av0 = *(const bf16x8*)&S.hA[lr][k0*32 + lg*8];
        bf16x8 av1 = *(const bf16x8*)&S.hA[16+lr][k0*32 + lg*8];
        acc0 = MFMA16(av0, bw[k0], acc0, 0,0,0);
        acc1 = MFMA16(av1, bw[k0], acc1, 0,0,0);
      }
    }
    __syncthreads();
    #pragma unroll
    for (int reg=0; reg<4; ++reg){
      S.Cs[lg*4+reg][w*16+lr]    = acc0[reg];
      S.Cs[16+lg*4+reg][w*16+lr] = acc1[reg];
    }
    __syncthreads();
    if (col0 + 8 <= V_){
      float4 v0, v1;
      v0.x = fminf(fmaxf(S.Cs[srow][scc+0] + bb[0], -10.f), 10.f);
      v0.y = fminf(fmaxf(S.Cs[srow][scc+1] + bb[1], -10.f), 10.f);
      v0.z = fminf(fmaxf(S.Cs[srow][scc+2] + bb[2], -10.f), 10.f);
      v0.w = fminf(fmaxf(S.Cs[srow][scc+3] + bb[3], -10.f), 10.f);
      v1.x = fminf(fmaxf(S.Cs[srow][scc+4] + bb[4], -10.f), 10.f);
      v1.y = fminf(fmaxf(S.Cs[srow][scc+5] + bb[5], -10.f), 10.f);
      v1.z = fminf(fmaxf(S.Cs[srow][scc+6] + bb[6], -10.f), 10.f);
      v1.w = fminf(fmaxf(S.Cs[srow][scc+7] + bb[7], -10.f), 10.f);
      float* o = out + ((size_t)srow*T_ + u)*V_ + col0;
      *(float4*)o = v0; *(float4*)(o+4) = v1;
    }
    __syncthreads();
  }
}

// ---------------- LY (R8-proven verbatim) ----------------
__launch_bounds__(1024)
__global__ void k_ly(const float* __restrict__ part1, const float* __restrict__ bias1p,
                     float* __restrict__ c1buf, u16* __restrict__ h1all,
                     const unsigned* __restrict__ Wd2, const float* __restrict__ bd,
                     const u16* __restrict__ att1b, const u16* __restrict__ enc16,
                     const float* __restrict__ Wf, const float* __restrict__ bfp,
                     const u16* __restrict__ embs, u16* __restrict__ xh0cur, int t){
  int b = blockIdx.x, tid = threadIdx.x;
  int l = tid & 63, wid = tid >> 6;
  __shared__ float g1s[2048];
  __shared__ float h1s[512];
  __shared__ float a2p[4][256];
  __shared__ float a2[256], ev[256], red[8], wfv[256], bdv[256];
  __shared__ float cb[4][256][2];
  if (tid < 256){ wfv[tid] = Wf[tid]; bdv[tid] = bd[tid]; }
  float bf0 = bfp[0];

  if (t > 0){
    float acc0 = bias1p[tid], acc1 = bias1p[tid + 1024];
    #pragma unroll 4
    for (int s2=0; s2<32; ++s2){
      const float* pp = part1 + ((size_t)(s2*32 + b))*2048;
      acc0 += pp[tid];
      acc1 += pp[tid + 1024];
    }
    g1s[tid] = acc0; g1s[tid + 1024] = acc1;
    __syncthreads();
    if (tid < 512){
      int h = tid, s4 = h >> 4, c = h & 15, base = s4*64 + c;
      float gi = g1s[base], gf = g1s[base+16], gg = g1s[base+32], go = g1s[base+48];
      float cold = c1buf[b*512 + h];
      float cn = sigm(gf)*cold + sigm(gi)*tanhf(gg);
      c1buf[b*512 + h] = cn;
      float hn = sigm(go)*tanhf(cn);
      h1s[h] = hn;
      h1all[((size_t)b*T_ + (t-1))*512 + h] = f2b(hn);
    }
  } else {
    if (tid < 512) h1s[tid] = 0.f;
  }
  __syncthreads();
  if (t >= T_) return;

  {
    int n = tid & 255, kq = tid >> 8;
    float acc = 0.f;
    const unsigned* wp = Wd2 + (size_t)kq*64*256 + n;
    #pragma unroll 8
    for (int kp2 = 0; kp2 < 64; ++kp2){
      unsigned wv = wp[(size_t)kp2*256];
      int k0 = (kq*64 + kp2)*2;
      acc += h1s[k0]   * b2f((u16)(wv & 0xFFFFu))
           + h1s[k0+1] * b2f((u16)(wv >> 16));
    }
    a2p[kq][n] = acc;
  }
  __syncthreads();
  if (tid < 256) a2[tid] = a2p[0][tid] + a2p[1][tid] + a2p[2][tid] + a2p[3][tid] + bdv[tid];
  __syncthreads();
  for (int pi = 0; pi < 13; ++pi){
    int p = pi*16 + wid;
    if (p < P_){
      ushort4 av4 = *(const ushort4*)(att1b + (size_t)(b*P_ + p)*A_ + l*4);
      int j0 = l*4;
      float sum = fmaxf(b2f(av4.x)+a2[j0],  0.f)*wfv[j0]
                + fmaxf(b2f(av4.y)+a2[j0+1],0.f)*wfv[j0+1]
                + fmaxf(b2f(av4.z)+a2[j0+2],0.f)*wfv[j0+2]
                + fmaxf(b2f(av4.w)+a2[j0+3],0.f)*wfv[j0+3];
      #pragma unroll
      for (int off=32; off; off>>=1) sum += __shfl_xor(sum, off, 64);
      if (l == 0) ev[p] = sum + bf0;
    }
  }
  __syncthreads();
  if (tid < 256){
    float v = (tid < P_) ? ev[tid] : -1e30f;
    float m = v;
    #pragma unroll
    for (int off=32; off; off>>=1) m = fmaxf(m, __shfl_xor(m, off, 64));
    if (l == 0) red[wid] = m;
  }
  __syncthreads();
  float mg = fmaxf(fmaxf(red[0],red[1]), fmaxf(red[2],red[3]));
  if (tid < 256){
    float ex = (tid < P_) ? __expf(ev[tid] - mg) : 0.f;
    float ss = ex;
    #pragma unroll
    for (int off=32; off; off>>=1) ss += __shfl_xor(ss, off, 64);
    if (l == 0) red[4+wid] = ss;
    ev[tid] = ex;
  }
  __syncthreads();
  float inv = 1.f/(red[4]+red[5]+red[6]+red[7]);
  {
    int j = tid & 255, pq = tid >> 8;
    float A0 = 0.f, A1 = 0.f;
    const unsigned* ep = (const unsigned*)enc16 + ((size_t)b*P_ + pq*49)*256 + j;
    #pragma unroll 7
    for (int pi = 0; pi < 49; ++pi){
      unsigned vv = ep[(size_t)pi*256];
      float al = ev[pq*49 + pi];
      A0 += al * b2f((u16)(vv & 0xFFFFu));
      A1 += al * b2f((u16)(vv >> 16));
    }
    cb[pq][j][0] = A0; cb[pq][j][1] = A1;
  }
  __syncthreads();
  if (tid < 256){
    float c0 = (cb[0][tid][0]+cb[1][tid][0]+cb[2][tid][0]+cb[3][tid][0]) * inv;
    float c1 = (cb[0][tid][1]+cb[1][tid][1]+cb[2][tid][1]+cb[3][tid][1]) * inv;
    unsigned o = (unsigned)f2b(c0) | (((unsigned)f2b(c1)) << 16);
    *((unsigned*)(xh0cur + (size_t)b*1536 + 512) + tid) = o;
    ((unsigned*)(xh0cur + (size_t)b*1536))[tid] =
        ((const unsigned*)(embs + (size_t)(t*32+b)*E_))[tid];
  }
}

// ---------------- LX: 64 blocks = (slice s, batch-half); math identical to R13 ----------------
__launch_bounds__(1024)
__global__ void k_lx(const u16* __restrict__ xh0cur, u16* __restrict__ xh0nxt,
                     const u16* __restrict__ Wg0pk, const float* __restrict__ bias0p,
                     const u16* __restrict__ W1ppk, const u16* __restrict__ h1all,
                     float* __restrict__ c0buf, float* __restrict__ part1, int t){
  __shared__ float part[16][16][16];      // [kw][batch-in-half][col] 16 KB
  __shared__ float gsum[4][16][16];       // 4 KB
  __shared__ __align__(16) u16 As[16][40];
  int tid = threadIdx.x;
  int s = blockIdx.x >> 1, half = blockIdx.x & 1;
  int l = tid & 63, kw = tid >> 6, lr = l & 15, lg = l >> 4;
  int babs = half*16 + lr;                // this wave-lane's batch (A rows = 16 batches of half)

  // gates0 A-fragments for this half's batches
  bf16x8 a[3];
  #pragma unroll
  for (int ks=0;ks<3;ks++)
    a[ks] = *(const bf16x8*)(xh0cur + (size_t)babs*1536 + kw*96 + ks*32 + lg*8);
  // stage h1(t-1) slice for this half into As[*][16..32)
  if (tid < 128){
    int bb = tid >> 3, kk = (tid & 7)*2;
    unsigned hv = 0;
    if (t > 0) hv = *(const unsigned*)(h1all + ((size_t)(half*16+bb)*T_ + (t-1))*512 + s*16 + kk);
    *(unsigned*)&As[bb][16+kk] = hv;
  }
  for (int q=0;q<4;q++){
    fx4 acc0 = (fx4){0,0,0,0};
    const u16* wp = Wg0pk + (size_t)(((s*4+q)*4 + (kw>>2))*12 + (kw&3)*3)*512 + l*8;
    #pragma unroll
    for (int ks=0;ks<3;ks++){
      bf16x8 bf8 = *(const bf16x8*)(wp + ks*512);
      acc0 = MFMA16(a[ks], bf8, acc0, 0,0,0);
    }
    #pragma unroll
    for (int reg=0;reg<4;reg++)
      part[kw][lg*4+reg][lr] = acc0[reg];
    __syncthreads();
    if (tid < 256){
      int bb = tid >> 4, c = tid & 15;
      float g = bias0p[s*64 + q*16 + c];
      #pragma unroll
      for (int kw2=0; kw2<16; ++kw2) g += part[kw2][bb][c];
      gsum[q][bb][c] = g;
    }
    __syncthreads();
  }
  // cell0 -> h0(t) for this half's 16 batches
  if (tid < 256){
    int bb = tid >> 4, c = tid & 15;
    int h = s*16 + c, ba = half*16 + bb;
    float gi = gsum[0][bb][c], gf = gsum[1][bb][c], gg = gsum[2][bb][c], go = gsum[3][bb][c];
    float cold = c0buf[ba*512 + h];
    float cn = sigm(gf)*cold + sigm(gi)*tanhf(gg);
    c0buf[ba*512 + h] = cn;
    u16 hb = f2b(sigm(go)*tanhf(cn));
    xh0nxt[(size_t)ba*1536 + 1024 + h] = hb;
    As[bb][c] = hb;
  }
  __syncthreads();
  // gates1 partials: rows = this half's 16 batches; all 128 nf covered (wave kw -> nf kw*8+i)
  bf16x8 pa0 = *(const bf16x8*)&As[lr][lg*8];
  #pragma unroll 2
  for (int i=0;i<8;i++){
    int nf = kw*8 + i;
    bf16x8 bf8 = *(const bf16x8*)(W1ppk + (size_t)(s*128 + nf)*512 + l*8);
    fx4 A0 = MFMA16(pa0, bf8, (fx4){0,0,0,0}, 0,0,0);
    float* o = part1 + ((size_t)s*32 + half*16)*2048 + nf*16 + lr;
    #pragma unroll
    for (int reg=0;reg<4;reg++)
      o[(size_t)(lg*4+reg)*2048] = A0[reg];
  }
}

extern "C" void kernel_launch(void* const* d_in, const int* in_sizes, int n_in,
                              void* d_out, int out_size, void* d_ws, size_t ws_size,
                              hipStream_t stream){
  (void)in_sizes; (void)n_in; (void)out_size; (void)ws_size;
  const float* features = (const float*)d_in[0];
  const int*   captions = (const int*)d_in[1];
  const float* Wad  = (const float*)d_in[2];
  const float* bad  = (const float*)d_in[3];
  const float* g_ad = (const float*)d_in[4];
  const float* b_ad = (const float*)d_in[5];
  const float* We   = (const float*)d_in[6];
  const float* be   = (const float*)d_in[7];
  const float* Wd   = (const float*)d_in[8];
  const float* bd   = (const float*)d_in[9];
  const float* Wf   = (const float*)d_in[10];
  const float* bfp  = (const float*)d_in[11];
  const float* emb  = (const float*)d_in[12];
  const float* W_ih0 = (const float*)d_in[13];
  const float* W_hh0 = (const float*)d_in[14];
  const float* b_ih0 = (const float*)d_in[15];
  const float* b_hh0 = (const float*)d_in[16];
  const float* W_ih1 = (const float*)d_in[17];
  const float* W_hh1 = (const float*)d_in[18];
  const float* b_ih1 = (const float*)d_in[19];
  const float* b_hh1 = (const float*)d_in[20];
  const float* W1  = (const float*)d_in[21];
  const float* b1  = (const float*)d_in[22];
  const float* g1  = (const float*)d_in[23];
  const float* bb1 = (const float*)d_in[24];
  const float* W2  = (const float*)d_in[25];
  const float* b2  = (const float*)d_in[26];
  float* out = (float*)d_out;

  char* wsb = (char*)d_ws;
  size_t off = 0;
  auto alloc = [&](size_t bytes)->char*{
    char* p = wsb + off; off += (bytes + 255) & ~(size_t)255; return p;
  };
  u16* fb16    = (u16*)alloc((size_t)6272*2048*2);
  u16* Wad16   = (u16*)alloc((size_t)512*2048*2);
  u16* We16    = (u16*)alloc((size_t)256*512*2);
  u16* W1_16   = (u16*)alloc((size_t)256*512*2);
  u16* W2pk    = (u16*)alloc((size_t)1875*8*512*2);
  unsigned* Wd2 = (unsigned*)alloc((size_t)256*256*4);
  u16* Wg0pk   = (u16*)alloc((size_t)2048*1536*2);
  u16* W1ppk   = (u16*)alloc((size_t)32*128*512*2);
  float* bias0p = (float*)alloc(2048*4);
  float* bias1p = (float*)alloc(2048*4);
  u16* embs16  = (u16*)alloc((size_t)1024*512*2);
  u16* pre16   = (u16*)alloc((size_t)6272*512*2);
  u16* enc16   = (u16*)alloc((size_t)6272*512*2);
  u16* att1_16 = (u16*)alloc((size_t)6272*256*2);
  u16* xh0     = (u16*)alloc((size_t)2*32*1536*2);   // zeroed region start
  float* c0buf = (float*)alloc(32*512*4);
  float* c1buf = (float*)alloc(32*512*4);            // zeroed region end
  float* part1 = (float*)alloc((size_t)32*32*2048*4);
  u16* h1all16 = (u16*)alloc((size_t)1024*512*2);
  u16* hid16   = (u16*)alloc((size_t)1024*256*2);

  hipMemsetAsync(xh0, 0, 196608 + 65536 + 65536, stream);

  // prep: one merged launch (includes features->bf16)
  k_prep<<<PREP_BLOCKS,256,0,stream>>>(Wad, We, W1, W2, Wd,
                                       W_ih0, W_hh0, W_ih1, W_hh1,
                                       b_ih0, b_hh0, b_ih1, b_hh1,
                                       emb, captions, features,
                                       Wad16, We16, W1_16, W2pk, Wd2,
                                       Wg0pk, W1ppk, bias0p, bias1p, embs16, fb16);

  // encoder: bf16 adapter + XCD-panel swizzle (untested combo), att1 swizzled
  k_gemm<0,64,64,64,8><<<832,256,0,stream>>>(fb16, Wad16, bad, pre16, 6272, 512, 2048);
  k_ln1<<<6272,64,0,stream>>>(pre16, g_ad, b_ad, enc16);
  k_gemm<1,64,64,64,4><<<416,256,0,stream>>>(enc16, We16, be, att1_16, 6272, 256, 512);

  // recurrence: k_ly 32 blocks, k_lx 64 blocks (batch-half split, math-identical)
  u16* xb[2] = { xh0, xh0 + 32*1536 };
  for (int t = 0; t < T_; ++t){
    k_ly<<<32,1024,0,stream>>>(part1, bias1p, c1buf, h1all16, Wd2, bd,
                               att1_16, enc16, Wf, bfp, embs16, xb[t&1], t);
    k_lx<<<64,1024,0,stream>>>(xb[t&1], xb[1-(t&1)], Wg0pk, bias0p,
                               W1ppk, h1all16, c0buf, part1, t);
  }
  // final finish: h1(31) -> h1all
  k_ly<<<32,1024,0,stream>>>(part1, bias1p, c1buf, h1all16, Wd2, bd,
                             att1_16, enc16, Wf, bfp, embs16, xb[0], T_);

  // tail: fused W1+LN+relu, then register-resident packed-W2 head
  k_w1<<<32,1024,0,stream>>>(h1all16, W1_16, b1, g1, bb1, hid16);
  k_head<<<dim3(118,2),1024,0,stream>>>(hid16, W2pk, b2, out);
}

// Round 17
// 1207.451 us; speedup vs baseline: 1.2495x; 1.0300x over previous
//
#include <hip/hip_runtime.h>

#define B_ 32
#define P_ 196
#define T_ 32
#define E_ 512
#define H_ 512
#define A_ 256
#define V_ 30000
#define FEAT_ 2048

typedef unsigned short u16;
typedef __attribute__((ext_vector_type(8))) short bf16x8;
typedef __attribute__((ext_vector_type(4))) float fx4;

#define MFMA16 __builtin_amdgcn_mfma_f32_16x16x32_bf16

__device__ __forceinline__ u16 f2b(float f){
  unsigned u = __builtin_bit_cast(unsigned, f);
  u += 0x7FFFu + ((u >> 16) & 1u);
  return (u16)(u >> 16);
}
__device__ __forceinline__ float b2f(u16 h){
  unsigned u = ((unsigned)h) << 16;
  return __builtin_bit_cast(float, u);
}
__device__ __forceinline__ float sigm(float x){ return 1.f/(1.f + __expf(-x)); }

// ================= merged prep (R16-proven) =================
#define PREP_BLOCKS 31670
__global__ void k_prep(const float* __restrict__ Wad, const float* __restrict__ We,
                       const float* __restrict__ W1f, const float* __restrict__ W2f,
                       const float* __restrict__ Wd,
                       const float* __restrict__ Wih0, const float* __restrict__ Whh0,
                       const float* __restrict__ Wih1, const float* __restrict__ Whh1,
                       const float* __restrict__ bih0, const float* __restrict__ bhh0,
                       const float* __restrict__ bih1, const float* __restrict__ bhh1,
                       const float* __restrict__ emb, const int* __restrict__ cap,
                       const float* __restrict__ feat,
                       u16* __restrict__ Wad16, u16* __restrict__ We16,
                       u16* __restrict__ W1_16, u16* __restrict__ W2pk,
                       unsigned* __restrict__ Wd2, u16* __restrict__ Wg0pk,
                       u16* __restrict__ W1ppk, float* __restrict__ bias0p,
                       float* __restrict__ bias1p, u16* __restrict__ embs16,
                       u16* __restrict__ fb16){
  int bid = blockIdx.x, tid = threadIdx.x;
  if (bid < 12288){
    int eid = bid*256 + tid;
    int j = eid & 7, l = (eid >> 3) & 63, frag = eid >> 9;
    int ks = frag % 12; int rest = frag / 12;
    int kw = rest & 3, q = (rest >> 2) & 3, s = rest >> 4;
    int n = q*512 + s*16 + (l & 15);
    int k = kw*384 + ks*32 + ((l >> 4) << 3) + j;
    float v = (k < 1024) ? Wih0[(size_t)n*1024 + k] : Whh0[(size_t)n*512 + (k - 1024)];
    Wg0pk[eid] = f2b(v);
  } else if (bid < 20480){
    int eid = (bid-12288)*256 + tid;
    int j = eid & 7, l = (eid >> 3) & 63, f = eid >> 9;
    int nf = f & 127, s = f >> 7;
    int np = nf*16 + (l & 15);
    int k = ((l >> 4) << 3) + j;
    int orig = ((np >> 4) & 3)*512 + (np >> 6)*16 + (np & 15);
    float v = (k < 16) ? Wih1[(size_t)orig*512 + s*16 + k]
                       : Whh1[(size_t)orig*512 + s*16 + (k - 16)];
    W1ppk[eid] = f2b(v);
  } else if (bid < 24230){
    int i = (bid-20480)*256 + tid;
    int l = i & 63, kc = (i >> 6) & 7, nf = i >> 9;
    int row = nf*16 + (l & 15);
    int col = kc*32 + (l >> 4)*8;
    const float4* s = (const float4*)(W2f + (size_t)row*256 + col);
    float4 a = s[0], b = s[1];
    ushort4* d = (ushort4*)(W2pk + (size_t)i*8);
    d[0] = make_ushort4(f2b(a.x), f2b(a.y), f2b(a.z), f2b(a.w));
    d[1] = make_ushort4(f2b(b.x), f2b(b.y), f2b(b.z), f2b(b.w));
  } else if (bid < 24742){
    int i = (bid-24230)*256 + tid;
    const float4* s = (const float4*)Wad + (size_t)i*2;
    float4 a = s[0], b = s[1];
    ushort4* d = (ushort4*)Wad16 + (size_t)i*2;
    d[0] = make_ushort4(f2b(a.x), f2b(a.y), f2b(a.z), f2b(a.w));
    d[1] = make_ushort4(f2b(b.x), f2b(b.y), f2b(b.z), f2b(b.w));
  } else if (bid < 24806){
    int i = (bid-24742)*256 + tid;
    const float4* s = (const float4*)We + (size_t)i*2;
    float4 a = s[0], b = s[1];
    ushort4* d = (ushort4*)We16 + (size_t)i*2;
    d[0] = make_ushort4(f2b(a.x), f2b(a.y), f2b(a.z), f2b(a.w));
    d[1] = make_ushort4(f2b(b.x), f2b(b.y), f2b(b.z), f2b(b.w));
  } else if (bid < 24870){
    int i = (bid-24806)*256 + tid;
    const float4* s = (const float4*)W1f + (size_t)i*2;
    float4 a = s[0], b = s[1];
    ushort4* d = (ushort4*)W1_16 + (size_t)i*2;
    d[0] = make_ushort4(f2b(a.x), f2b(a.y), f2b(a.z), f2b(a.w));
    d[1] = make_ushort4(f2b(b.x), f2b(b.y), f2b(b.z), f2b(b.w));
  } else if (bid < 25126){
    int i = (bid-24870)*256 + tid;
    int n = i & 255, kp = i >> 8;
    unsigned lo = f2b(Wd[n*512 + 2*kp]);
    unsigned hi = f2b(Wd[n*512 + 2*kp + 1]);
    Wd2[i] = lo | (hi << 16);
  } else if (bid < 25134){
    int n = (bid-25126)*256 + tid;
    int c = n & 15, q = (n >> 4) & 3, s = n >> 6;
    int orig = q*512 + s*16 + c;
    bias0p[n] = bih0[orig] + bhh0[orig];
  } else if (bid < 25142){
    int n = (bid-25134)*256 + tid;
    int c = n & 15, q = (n >> 4) & 3, s = n >> 6;
    int orig = q*512 + s*16 + c;
    bias1p[n] = bih1[orig] + bhh1[orig];
  } else if (bid < 25398){
    int r = (bid-25142)*4 + (tid >> 6), l = tid & 63;
    int t = r >> 5, b = r & 31;
    int c = cap[b*T_ + t];
    const float4* s = (const float4*)(emb + (size_t)c*E_) + l*2;
    float4 a = s[0], bb = s[1];
    ushort4* d = (ushort4*)(embs16 + (size_t)r*E_) + l*2;
    d[0] = make_ushort4(f2b(a.x), f2b(a.y), f2b(a.z), f2b(a.w));
    d[1] = make_ushort4(f2b(bb.x), f2b(bb.y), f2b(bb.z), f2b(bb.w));
  } else {
    int i = (bid-25398)*256 + tid;
    const float4* s = (const float4*)feat + (size_t)i*2;
    float4 a = s[0], b = s[1];
    ushort4* d = (ushort4*)fb16 + (size_t)i*2;
    d[0] = make_ushort4(f2b(a.x), f2b(a.y), f2b(a.z), f2b(a.w));
    d[1] = make_ushort4(f2b(b.x), f2b(b.y), f2b(b.z), f2b(b.w));
  }
}

// ============ split-K adapter GEMM: f32 partials, no bias/act ============
// grid = NKQ * (8*NQ*13); kq in high bits; inner decode XCD-swizzled as before.
template<int BM, int BN, int KS, int NQ, int NKQ>
__launch_bounds__(256)
__global__ void k_gemmSK(const u16* __restrict__ A, const u16* __restrict__ W,
                         float* __restrict__ outP, int M, int N, int K){
  constexpr int NI = BN/32, MI = BM/32, SEGS = KS/8;
  __shared__ __align__(16) u16 As[BM][KS+8];
  __shared__ __align__(16) u16 Bs[BN][KS+8];
  int f = blockIdx.x;
  int inner = 8*NQ*((M/BM + 7)/8);
  int kq = f / inner; f %= inner;
  int p8 = f & 7; int rest = f >> 3;
  int q = rest % NQ; int pHigh = rest / NQ;
  int p = pHigh*8 + p8;
  if (p*BM >= M) return;
  int m0 = p*BM, n0 = q*BN;
  int kper = K / NKQ;
  int kbeg = kq * kper, kend = kbeg + kper;
  int tid = threadIdx.x;
  int l = tid & 63, w = tid >> 6;
  int wr = w >> 1, wc = w & 1;
  fx4 acc[MI][NI];
  #pragma unroll
  for (int i=0;i<MI;i++)
    #pragma unroll
    for (int j=0;j<NI;j++) acc[i][j] = (fx4){0.f,0.f,0.f,0.f};
  int lr = l & 15, lg = l >> 4;
  for (int k0 = kbeg; k0 < kend; k0 += KS){
    #pragma unroll
    for (int it=0; it<BM*SEGS/256; ++it){
      int flat = it*256 + tid, rr = flat/SEGS, cs = (flat%SEGS)*8;
      *(uint4*)&As[rr][cs] = *(const uint4*)(A + (size_t)(m0+rr)*K + k0 + cs);
    }
    #pragma unroll
    for (int it=0; it<BN*SEGS/256; ++it){
      int flat = it*256 + tid, rr = flat/SEGS, cs = (flat%SEGS)*8;
      *(uint4*)&Bs[rr][cs] = *(const uint4*)(W + (size_t)(n0+rr)*K + k0 + cs);
    }
    __syncthreads();
    #pragma unroll
    for (int kk=0; kk<KS/32; ++kk){
      bf16x8 av[MI], bv[NI];
      #pragma unroll
      for (int mi=0; mi<MI; mi++) av[mi] = *(const bf16x8*)&As[wr*(BM/2) + mi*16 + lr][kk*32 + lg*8];
      #pragma unroll
      for (int ni=0; ni<NI; ni++) bv[ni] = *(const bf16x8*)&Bs[wc*(BN/2) + ni*16 + lr][kk*32 + lg*8];
      #pragma unroll
      for (int mi=0; mi<MI; mi++)
        #pragma unroll
        for (int ni=0; ni<NI; ni++)
          acc[mi][ni] = MFMA16(av[mi], bv[ni], acc[mi][ni], 0, 0, 0);
    }
    __syncthreads();
  }
  #pragma unroll
  for (int mi=0; mi<MI; mi++)
    #pragma unroll
    for (int ni=0; ni<NI; ni++){
      int col = n0 + wc*(BN/2) + ni*16 + lr;
      #pragma unroll
      for (int reg=0; reg<4; reg++){
        int rowm = m0 + wr*(BM/2) + mi*16 + lg*4 + reg;
        outP[((size_t)kq*M + rowm)*N + col] = acc[mi][ni][reg];
      }
    }
}

// ============ encoder GEMM (att1), XCD-panel swizzle (R16-proven) ============
template<int MODE, int BM, int BN, int KS, int NQ>
__launch_bounds__(256)
__global__ void k_gemm(const u16* __restrict__ A, const u16* __restrict__ W,
                       const float* __restrict__ bias, u16* __restrict__ outB,
                       int M, int N, int K){
  constexpr int NI = BN/32, MI = BM/32, SEGS = KS/8;
  __shared__ __align__(16) u16 As[BM][KS+8];
  __shared__ __align__(16) u16 Bs[BN][KS+8];
  int f = blockIdx.x;
  int p8 = f & 7; int rest = f >> 3;
  int q = rest % NQ; int pHigh = rest / NQ;
  int p = pHigh*8 + p8;
  if (p*BM >= M) return;
  int m0 = p*BM, n0 = q*BN;
  int tid = threadIdx.x;
  int l = tid & 63, w = tid >> 6;
  int wr = w >> 1, wc = w & 1;
  fx4 acc[MI][NI];
  #pragma unroll
  for (int i=0;i<MI;i++)
    #pragma unroll
    for (int j=0;j<NI;j++) acc[i][j] = (fx4){0.f,0.f,0.f,0.f};
  int lr = l & 15, lg = l >> 4;
  for (int k0 = 0; k0 < K; k0 += KS){
    #pragma unroll
    for (int it=0; it<BM*SEGS/256; ++it){
      int flat = it*256 + tid, rr = flat/SEGS, cs = (flat%SEGS)*8;
      *(uint4*)&As[rr][cs] = *(const uint4*)(A + (size_t)(m0+rr)*K + k0 + cs);
    }
    uint4 z = {0u,0u,0u,0u};
    #pragma unroll
    for (int it=0; it<BN*SEGS/256; ++it){
      int flat = it*256 + tid, rr = flat/SEGS, cs = (flat%SEGS)*8;
      int rb = n0 + rr;
      *(uint4*)&Bs[rr][cs] = (rb < N) ? *(const uint4*)(W + (size_t)rb*K + k0 + cs) : z;
    }
    __syncthreads();
    #pragma unroll
    for (int kk=0; kk<KS/32; ++kk){
      bf16x8 av[MI], bv[NI];
      #pragma unroll
      for (int mi=0; mi<MI; mi++) av[mi] = *(const bf16x8*)&As[wr*(BM/2) + mi*16 + lr][kk*32 + lg*8];
      #pragma unroll
      for (int ni=0; ni<NI; ni++) bv[ni] = *(const bf16x8*)&Bs[wc*(BN/2) + ni*16 + lr][kk*32 + lg*8];
      #pragma unroll
      for (int mi=0; mi<MI; mi++)
        #pragma unroll
        for (int ni=0; ni<NI; ni++)
          acc[mi][ni] = MFMA16(av[mi], bv[ni], acc[mi][ni], 0, 0, 0);
    }
    __syncthreads();
  }
  #pragma unroll
  for (int mi=0; mi<MI; mi++)
    #pragma unroll
    for (int ni=0; ni<NI; ni++){
      int col = n0 + wc*(BN/2) + ni*16 + lr;
      if (col >= N) continue;
      float bvs = bias[col];
      #pragma unroll
      for (int reg=0; reg<4; reg++){
        int rowm = m0 + wr*(BM/2) + mi*16 + lg*4 + reg;
        float v = acc[mi][ni][reg] + bvs;
        if (MODE == 0) v = fmaxf(v, 0.f);
        outB[(size_t)rowm*N + col] = f2b(v);
      }
    }
}

// ---------------- LayerNorm 512 + split-K reduce + bias + relu (f32 partials in) ----------------
__global__ void k_ln1(const float* __restrict__ preP, const float* __restrict__ bad,
                      const float* __restrict__ g, const float* __restrict__ bt,
                      u16* __restrict__ enc){
  int row = blockIdx.x; int l = threadIdx.x;
  int c0 = l*8;
  float x[8];
  {
    const float4* p0 = (const float4*)(preP + ((size_t)0*6272 + row)*E_ + c0);
    const float4* p1 = (const float4*)(preP + ((size_t)1*6272 + row)*E_ + c0);
    const float4* p2 = (const float4*)(preP + ((size_t)2*6272 + row)*E_ + c0);
    const float4* p3 = (const float4*)(preP + ((size_t)3*6272 + row)*E_ + c0);
    float4 a0 = p0[0], b0 = p0[1];
    float4 a1 = p1[0], b1 = p1[1];
    float4 a2 = p2[0], b2 = p2[1];
    float4 a3 = p3[0], b3 = p3[1];
    x[0] = a0.x+a1.x+a2.x+a3.x; x[1] = a0.y+a1.y+a2.y+a3.y;
    x[2] = a0.z+a1.z+a2.z+a3.z; x[3] = a0.w+a1.w+a2.w+a3.w;
    x[4] = b0.x+b1.x+b2.x+b3.x; x[5] = b0.y+b1.y+b2.y+b3.y;
    x[6] = b0.z+b1.z+b2.z+b3.z; x[7] = b0.w+b1.w+b2.w+b3.w;
  }
  float s = 0.f;
  #pragma unroll
  for (int i=0;i<8;i++){ x[i] = fmaxf(x[i] + bad[c0+i], 0.f); s += x[i]; }
  #pragma unroll
  for (int off=32; off; off>>=1) s += __shfl_xor(s, off, 64);
  float mean = s * (1.f/512.f);
  float vs = 0.f;
  #pragma unroll
  for (int i=0;i<8;i++){ float d = x[i]-mean; vs += d*d; }
  #pragma unroll
  for (int off=32; off; off>>=1) vs += __shfl_xor(vs, off, 64);
  float inv = rsqrtf(vs*(1.f/512.f) + 1e-5f);
  u16 o[8];
  #pragma unroll
  for (int i=0;i<8;i++) o[i] = f2b((x[i]-mean)*inv*g[c0+i] + bt[c0+i]);
  ushort4* d = (ushort4*)(enc + (size_t)row*E_ + c0);
  d[0] = make_ushort4(o[0],o[1],o[2],o[3]);
  d[1] = make_ushort4(o[4],o[5],o[6],o[7]);
}

// ---------------- W1 GEMM + LN + relu (R13-proven) ----------------
__device__ __forceinline__ void w1ln_block(const u16* __restrict__ h1all,
    const u16* __restrict__ W1, const float* __restrict__ b1,
    const float* __restrict__ g1v, const float* __restrict__ bb1,
    u16* __restrict__ hid, int u, int tid, float* red2, float* mv){
  int l = tid & 63, w = tid >> 6, lr = l & 15, lg = l >> 4;
  fx4 acc[2] = {{0,0,0,0},{0,0,0,0}};
  for (int k0 = 0; k0 < 512; k0 += 32){
    bf16x8 bv  = *(const bf16x8*)(W1 + (size_t)(w*16+lr)*512 + k0 + lg*8);
    bf16x8 av0 = *(const bf16x8*)(h1all + ((size_t)lr*T_ + u)*512 + k0 + lg*8);
    bf16x8 av1 = *(const bf16x8*)(h1all + ((size_t)(16+lr)*T_ + u)*512 + k0 + lg*8);
    acc[0] = MFMA16(av0, bv, acc[0], 0,0,0);
    acc[1] = MFMA16(av1, bv, acc[1], 0,0,0);
  }
  int col = w*16 + lr;
  float bc = b1[col];
  float val[2][4], s1[2][4], s2[2][4];
  #pragma unroll
  for (int mi=0;mi<2;mi++)
    #pragma unroll
    for (int reg=0;reg<4;reg++){
      float v = acc[mi][reg] + bc;
      val[mi][reg] = v; s1[mi][reg] = v; s2[mi][reg] = v*v;
    }
  #pragma unroll
  for (int off=1; off<16; off<<=1){
    #pragma unroll
    for (int mi=0;mi<2;mi++)
      #pragma unroll
      for (int reg=0;reg<4;reg++){
        s1[mi][reg] += __shfl_xor(s1[mi][reg], off, 64);
        s2[mi][reg] += __shfl_xor(s2[mi][reg], off, 64);
      }
  }
  if (lr == 0){
    #pragma unroll
    for (int mi=0;mi<2;mi++)
      #pragma unroll
      for (int reg=0;reg<4;reg++){
        int row = mi*16 + lg*4 + reg;
        red2[(0*16 + w)*32 + row] = s1[mi][reg];
        red2[(16   + w)*32 + row] = s2[mi][reg];
      }
  }
  __syncthreads();
  if (tid < 64){
    int which = tid >> 5, row = tid & 31;
    float s = 0.f;
    #pragma unroll
    for (int ww=0; ww<16; ++ww) s += red2[(which*16 + ww)*32 + row];
    mv[which*32 + row] = s;
  }
  __syncthreads();
  #pragma unroll
  for (int mi=0;mi<2;mi++)
    #pragma unroll
    for (int reg=0;reg<4;reg++){
      int row = mi*16 + lg*4 + reg;
      float mean = mv[row] * (1.f/256.f);
      float var  = mv[32+row] * (1.f/256.f) - mean*mean;
      float inv  = rsqrtf(var + 1e-5f);
      float o = fmaxf((val[mi][reg]-mean)*inv*g1v[col] + bb1[col], 0.f);
      hid[((size_t)u*32 + row)*256 + col] = f2b(o);
    }
}

__launch_bounds__(1024)
__global__ void k_w1(const u16* __restrict__ h1all, const u16* __restrict__ W1_16,
                     const float* __restrict__ b1, const float* __restrict__ g1v,
                     const float* __restrict__ bb1, u16* __restrict__ hid16){
  __shared__ float red2[1024];
  __shared__ float mv[64];
  w1ln_block(h1all, W1_16, b1, g1v, bb1, hid16, blockIdx.x, threadIdx.x, red2, mv);
}

// ---------------- head (R13-proven) ----------------
__launch_bounds__(1024)
__global__ void k_head(const u16* __restrict__ hid, const u16* __restrict__ W2pk,
                       const float* __restrict__ b2, float* __restrict__ out){
  __shared__ __align__(16) union { u16 hA[32][264]; float Cs[32][260]; } S;
  int c = blockIdx.x, uh = blockIdx.y, tid = threadIdx.x;
  int l = tid & 63, w = tid >> 6, lr = l & 15, lg = l >> 4;
  int nf = c*16 + w;
  bool valid = nf < 1875;
  bf16x8 bw[8];
  if (valid){
    const u16* wp = W2pk + (size_t)nf*4096 + l*8;
    #pragma unroll
    for (int k0=0;k0<8;k0++) bw[k0] = *(const bf16x8*)(wp + k0*512);
  }
  int srow = tid >> 5, scc = (tid & 31)*8;
  int col0 = c*256 + scc;
  float bb[8];
  #pragma unroll
  for (int j=0;j<8;j++) bb[j] = (col0 + j < V_) ? b2[col0 + j] : 0.f;

  for (int ui=0; ui<16; ++ui){
    int u = uh*16 + ui;
    { int arow = tid >> 5, ak = (tid & 31)*8;
      *(uint4*)&S.hA[arow][ak] = *(const uint4*)(hid + ((size_t)u*32 + arow)*256 + ak); }
    __syncthreads();
    fx4 acc0 = {0,0,0,0}, acc1 = {0,0,0,0};
    if (valid){
      #pragma unroll
      for (int k0=0;k0<8;k0++){
        bf16x8 av0 = *(const bf16x8*)&S.hA[lr][k0*32 + lg*8];
        bf16x8 av1 = *(const bf16x8*)&S.hA[16+lr][k0*32 + lg*8];
        acc0 = MFMA16(av0, bw[k0], acc0, 0,0,0);
        acc1 = MFMA16(av1, bw[k0], acc1, 0,0,0);
      }
    }
    __syncthreads();
    #pragma unroll
    for (int reg=0; reg<4; ++reg){
      S.Cs[lg*4+reg][w*16+lr]    = acc0[reg];
      S.Cs[16+lg*4+reg][w*16+lr] = acc1[reg];
    }
    __syncthreads();
    if (col0 + 8 <= V_){
      float4 v0, v1;
      v0.x = fminf(fmaxf(S.Cs[srow][scc+0] + bb[0], -10.f), 10.f);
      v0.y = fminf(fmaxf(S.Cs[srow][scc+1] + bb[1], -10.f), 10.f);
      v0.z = fminf(fmaxf(S.Cs[srow][scc+2] + bb[2], -10.f), 10.f);
      v0.w = fminf(fmaxf(S.Cs[srow][scc+3] + bb[3], -10.f), 10.f);
      v1.x = fminf(fmaxf(S.Cs[srow][scc+4] + bb[4], -10.f), 10.f);
      v1.y = fminf(fmaxf(S.Cs[srow][scc+5] + bb[5], -10.f), 10.f);
      v1.z = fminf(fmaxf(S.Cs[srow][scc+6] + bb[6], -10.f), 10.f);
      v1.w = fminf(fmaxf(S.Cs[srow][scc+7] + bb[7], -10.f), 10.f);
      float* o = out + ((size_t)srow*T_ + u)*V_ + col0;
      *(float4*)o = v0; *(float4*)(o+4) = v1;
    }
    __syncthreads();
  }
}

// ---------------- LY (R8-proven; part1 unroll 8) ----------------
__launch_bounds__(1024)
__global__ void k_ly(const float* __restrict__ part1, const float* __restrict__ bias1p,
                     float* __restrict__ c1buf, u16* __restrict__ h1all,
                     const unsigned* __restrict__ Wd2, const float* __restrict__ bd,
                     const u16* __restrict__ att1b, const u16* __restrict__ enc16,
                     const float* __restrict__ Wf, const float* __restrict__ bfp,
                     const u16* __restrict__ embs, u16* __restrict__ xh0cur, int t){
  int b = blockIdx.x, tid = threadIdx.x;
  int l = tid & 63, wid = tid >> 6;
  __shared__ float g1s[2048];
  __shared__ float h1s[512];
  __shared__ float a2p[4][256];
  __shared__ float a2[256], ev[256], red[8], wfv[256], bdv[256];
  __shared__ float cb[4][256][2];
  if (tid < 256){ wfv[tid] = Wf[tid]; bdv[tid] = bd[tid]; }
  float bf0 = bfp[0];

  if (t > 0){
    float acc0 = bias1p[tid], acc1 = bias1p[tid + 1024];
    #pragma unroll 8
    for (int s2=0; s2<32; ++s2){
      const float* pp = part1 + ((size_t)(s2*32 + b))*2048;
      acc0 += pp[tid];
      acc1 += pp[tid + 1024];
    }
    g1s[tid] = acc0; g1s[tid + 1024] = acc1;
    __syncthreads();
    if (tid < 512){
      int h = tid, s4 = h >> 4, c = h & 15, base = s4*64 + c;
      float gi = g1s[base], gf = g1s[base+16], gg = g1s[base+32], go = g1s[base+48];
      float cold = c1buf[b*512 + h];
      float cn = sigm(gf)*cold + sigm(gi)*tanhf(gg);
      c1buf[b*512 + h] = cn;
      float hn = sigm(go)*tanhf(cn);
      h1s[h] = hn;
      h1all[((size_t)b*T_ + (t-1))*512 + h] = f2b(hn);
    }
  } else {
    if (tid < 512) h1s[tid] = 0.f;
  }
  __syncthreads();
  if (t >= T_) return;

  {
    int n = tid & 255, kq = tid >> 8;
    float acc = 0.f;
    const unsigned* wp = Wd2 + (size_t)kq*64*256 + n;
    #pragma unroll 8
    for (int kp2 = 0; kp2 < 64; ++kp2){
      unsigned wv = wp[(size_t)kp2*256];
      int k0 = (kq*64 + kp2)*2;
      acc += h1s[k0]   * b2f((u16)(wv & 0xFFFFu))
           + h1s[k0+1] * b2f((u16)(wv >> 16));
    }
    a2p[kq][n] = acc;
  }
  __syncthreads();
  if (tid < 256) a2[tid] = a2p[0][tid] + a2p[1][tid] + a2p[2][tid] + a2p[3][tid] + bdv[tid];
  __syncthreads();
  for (int pi = 0; pi < 13; ++pi){
    int p = pi*16 + wid;
    if (p < P_){
      ushort4 av4 = *(const ushort4*)(att1b + (size_t)(b*P_ + p)*A_ + l*4);
      int j0 = l*4;
      float sum = fmaxf(b2f(av4.x)+a2[j0],  0.f)*wfv[j0]
                + fmaxf(b2f(av4.y)+a2[j0+1],0.f)*wfv[j0+1]
                + fmaxf(b2f(av4.z)+a2[j0+2],0.f)*wfv[j0+2]
                + fmaxf(b2f(av4.w)+a2[j0+3],0.f)*wfv[j0+3];
      #pragma unroll
      for (int off=32; off; off>>=1) sum += __shfl_xor(sum, off, 64);
      if (l == 0) ev[p] = sum + bf0;
    }
  }
  __syncthreads();
  if (tid < 256){
    float v = (tid < P_) ? ev[tid] : -1e30f;
    float m = v;
    #pragma unroll
    for (int off=32; off; off>>=1) m = fmaxf(m, __shfl_xor(m, off, 64));
    if (l == 0) red[wid] = m;
  }
  __syncthreads();
  float mg = fmaxf(fmaxf(red[0],red[1]), fmaxf(red[2],red[3]));
  if (tid < 256){
    float ex = (tid < P_) ? __expf(ev[tid] - mg) : 0.f;
    float ss = ex;
    #pragma unroll
    for (int off=32; off; off>>=1) ss += __shfl_xor(ss, off, 64);
    if (l == 0) red[4+wid] = ss;
    ev[tid] = ex;
  }
  __syncthreads();
  float inv = 1.f/(red[4]+red[5]+red[6]+red[7]);
  {
    int j = tid & 255, pq = tid >> 8;
    float A0 = 0.f, A1 = 0.f;
    const unsigned* ep = (const unsigned*)enc16 + ((size_t)b*P_ + pq*49)*256 + j;
    #pragma unroll 7
    for (int pi = 0; pi < 49; ++pi){
      unsigned vv = ep[(size_t)pi*256];
      float al = ev[pq*49 + pi];
      A0 += al * b2f((u16)(vv & 0xFFFFu));
      A1 += al * b2f((u16)(vv >> 16));
    }
    cb[pq][j][0] = A0; cb[pq][j][1] = A1;
  }
  __syncthreads();
  if (tid < 256){
    float c0 = (cb[0][tid][0]+cb[1][tid][0]+cb[2][tid][0]+cb[3][tid][0]) * inv;
    float c1 = (cb[0][tid][1]+cb[1][tid][1]+cb[2][tid][1]+cb[3][tid][1]) * inv;
    unsigned o = (unsigned)f2b(c0) | (((unsigned)f2b(c1)) << 16);
    *((unsigned*)(xh0cur + (size_t)b*1536 + 512) + tid) = o;
    ((unsigned*)(xh0cur + (size_t)b*1536))[tid] =
        ((const unsigned*)(embs + (size_t)(t*32+b)*E_))[tid];
  }
}

// ---------------- LX: 64 blocks = (slice s, batch-half) (R16-proven) ----------------
__launch_bounds__(1024)
__global__ void k_lx(const u16* __restrict__ xh0cur, u16* __restrict__ xh0nxt,
                     const u16* __restrict__ Wg0pk, const float* __restrict__ bias0p,
                     const u16* __restrict__ W1ppk, const u16* __restrict__ h1all,
                     float* __restrict__ c0buf, float* __restrict__ part1, int t){
  __shared__ float part[16][16][16];
  __shared__ float gsum[4][16][16];
  __shared__ __align__(16) u16 As[16][40];
  int tid = threadIdx.x;
  int s = blockIdx.x >> 1, half = blockIdx.x & 1;
  int l = tid & 63, kw = tid >> 6, lr = l & 15, lg = l >> 4;
  int babs = half*16 + lr;

  bf16x8 a[3];
  #pragma unroll
  for (int ks=0;ks<3;ks++)
    a[ks] = *(const bf16x8*)(xh0cur + (size_t)babs*1536 + kw*96 + ks*32 + lg*8);
  if (tid < 128){
    int bb = tid >> 3, kk = (tid & 7)*2;
    unsigned hv = 0;
    if (t > 0) hv = *(const unsigned*)(h1all + ((size_t)(half*16+bb)*T_ + (t-1))*512 + s*16 + kk);
    *(unsigned*)&As[bb][16+kk] = hv;
  }
  for (int q=0;q<4;q++){
    fx4 acc0 = (fx4){0,0,0,0};
    const u16* wp = Wg0pk + (size_t)(((s*4+q)*4 + (kw>>2))*12 + (kw&3)*3)*512 + l*8;
    #pragma unroll
    for (int ks=0;ks<3;ks++){
      bf16x8 bf8 = *(const bf16x8*)(wp + ks*512);
      acc0 = MFMA16(a[ks], bf8, acc0, 0,0,0);
    }
    #pragma unroll
    for (int reg=0;reg<4;reg++)
      part[kw][lg*4+reg][lr] = acc0[reg];
    __syncthreads();
    if (tid < 256){
      int bb = tid >> 4, c = tid & 15;
      float g = bias0p[s*64 + q*16 + c];
      #pragma unroll
      for (int kw2=0; kw2<16; ++kw2) g += part[kw2][bb][c];
      gsum[q][bb][c] = g;
    }
    __syncthreads();
  }
  if (tid < 256){
    int bb = tid >> 4, c = tid & 15;
    int h = s*16 + c, ba = half*16 + bb;
    float gi = gsum[0][bb][c], gf = gsum[1][bb][c], gg = gsum[2][bb][c], go = gsum[3][bb][c];
    float cold = c0buf[ba*512 + h];
    float cn = sigm(gf)*cold + sigm(gi)*tanhf(gg);
    c0buf[ba*512 + h] = cn;
    u16 hb = f2b(sigm(go)*tanhf(cn));
    xh0nxt[(size_t)ba*1536 + 1024 + h] = hb;
    As[bb][c] = hb;
  }
  __syncthreads();
  bf16x8 pa0 = *(const bf16x8*)&As[lr][lg*8];
  #pragma unroll 2
  for (int i=0;i<8;i++){
    int nf = kw*8 + i;
    bf16x8 bf8 = *(const bf16x8*)(W1ppk + (size_t)(s*128 + nf)*512 + l*8);
    fx4 A0 = MFMA16(pa0, bf8, (fx4){0,0,0,0}, 0,0,0);
    float* o = part1 + ((size_t)s*32 + half*16)*2048 + nf*16 + lr;
    #pragma unroll
    for (int reg=0;reg<4;reg++)
      o[(size_t)(lg*4+reg)*2048] = A0[reg];
  }
}

extern "C" void kernel_launch(void* const* d_in, const int* in_sizes, int n_in,
                              void* d_out, int out_size, void* d_ws, size_t ws_size,
                              hipStream_t stream){
  (void)in_sizes; (void)n_in; (void)out_size; (void)ws_size;
  const float* features = (const float*)d_in[0];
  const int*   captions = (const int*)d_in[1];
  const float* Wad  = (const float*)d_in[2];
  const float* bad  = (const float*)d_in[3];
  const float* g_ad = (const float*)d_in[4];
  const float* b_ad = (const float*)d_in[5];
  const float* We   = (const float*)d_in[6];
  const float* be   = (const float*)d_in[7];
  const float* Wd   = (const float*)d_in[8];
  const float* bd   = (const float*)d_in[9];
  const float* Wf   = (const float*)d_in[10];
  const float* bfp  = (const float*)d_in[11];
  const float* emb  = (const float*)d_in[12];
  const float* W_ih0 = (const float*)d_in[13];
  const float* W_hh0 = (const float*)d_in[14];
  const float* b_ih0 = (const float*)d_in[15];
  const float* b_hh0 = (const float*)d_in[16];
  const float* W_ih1 = (const float*)d_in[17];
  const float* W_hh1 = (const float*)d_in[18];
  const float* b_ih1 = (const float*)d_in[19];
  const float* b_hh1 = (const float*)d_in[20];
  const float* W1  = (const float*)d_in[21];
  const float* b1  = (const float*)d_in[22];
  const float* g1  = (const float*)d_in[23];
  const float* bb1 = (const float*)d_in[24];
  const float* W2  = (const float*)d_in[25];
  const float* b2  = (const float*)d_in[26];
  float* out = (float*)d_out;

  char* wsb = (char*)d_ws;
  size_t off = 0;
  auto alloc = [&](size_t bytes)->char*{
    char* p = wsb + off; off += (bytes + 255) & ~(size_t)255; return p;
  };
  u16* fb16    = (u16*)alloc((size_t)6272*2048*2);
  u16* Wad16   = (u16*)alloc((size_t)512*2048*2);
  u16* We16    = (u16*)alloc((size_t)256*512*2);
  u16* W1_16   = (u16*)alloc((size_t)256*512*2);
  u16* W2pk    = (u16*)alloc((size_t)1875*8*512*2);
  unsigned* Wd2 = (unsigned*)alloc((size_t)256*256*4);
  u16* Wg0pk   = (u16*)alloc((size_t)2048*1536*2);
  u16* W1ppk   = (u16*)alloc((size_t)32*128*512*2);
  float* bias0p = (float*)alloc(2048*4);
  float* bias1p = (float*)alloc(2048*4);
  u16* embs16  = (u16*)alloc((size_t)1024*512*2);
  u16* enc16   = (u16*)alloc((size_t)6272*512*2);
  u16* att1_16 = (u16*)alloc((size_t)6272*256*2);
  u16* xh0     = (u16*)alloc((size_t)2*32*1536*2);   // zeroed region start
  float* c0buf = (float*)alloc(32*512*4);
  float* c1buf = (float*)alloc(32*512*4);            // zeroed region end
  float* part1 = (float*)alloc((size_t)32*32*2048*4);
  u16* h1all16 = (u16*)alloc((size_t)1024*512*2);
  u16* hid16   = (u16*)alloc((size_t)1024*256*2);
  float* pre32f = (float*)alloc((size_t)4*6272*512*4);  // split-K partials (51.4 MB)

  hipMemsetAsync(xh0, 0, 196608 + 65536 + 65536, stream);

  // prep: one merged launch (includes features->bf16)
  k_prep<<<PREP_BLOCKS,256,0,stream>>>(Wad, We, W1, W2, Wd,
                                       W_ih0, W_hh0, W_ih1, W_hh1,
                                       b_ih0, b_hh0, b_ih1, b_hh1,
                                       emb, captions, features,
                                       Wad16, We16, W1_16, W2pk, Wd2,
                                       Wg0pk, W1ppk, bias0p, bias1p, embs16, fb16);

  // adapter: split-K 4-way (3328 blocks, 8 K-iters each) -> f32 partials
  k_gemmSK<64,64,64,8,4><<<3328,256,0,stream>>>(fb16, Wad16, pre32f, 6272, 512, 2048);
  // ln1: reduce 4 partials + bias + relu + LN
  k_ln1<<<6272,64,0,stream>>>(pre32f, bad, g_ad, b_ad, enc16);
  k_gemm<1,64,64,64,4><<<416,256,0,stream>>>(enc16, We16, be, att1_16, 6272, 256, 512);

  // recurrence: k_ly 32 blocks, k_lx 64 blocks
  u16* xb[2] = { xh0, xh0 + 32*1536 };
  for (int t = 0; t < T_; ++t){
    k_ly<<<32,1024,0,stream>>>(part1, bias1p, c1buf, h1all16, Wd2, bd,
                               att1_16, enc16, Wf, bfp, embs16, xb[t&1], t);
    k_lx<<<64,1024,0,stream>>>(xb[t&1], xb[1-(t&1)], Wg0pk, bias0p,
                               W1ppk, h1all16, c0buf, part1, t);
  }
  // final finish: h1(31) -> h1all
  k_ly<<<32,1024,0,stream>>>(part1, bias1p, c1buf, h1all16, Wd2, bd,
                             att1_16, enc16, Wf, bfp, embs16, xb[0], T_);

  // tail: fused W1+LN+relu, then register-resident packed-W2 head
  k_w1<<<32,1024,0,stream>>>(h1all16, W1_16, b1, g1, bb1, hid16);
  k_head<<<dim3(118,2),1024,0,stream>>>(hid16, W2pk, b2, out);
}

// Round 18
// 1199.938 us; speedup vs baseline: 1.2573x; 1.0063x over previous
//
#include <hip/hip_runtime.h>

#define B_ 32
#define P_ 196
#define T_ 32
#define E_ 512
#define H_ 512
#define A_ 256
#define V_ 30000
#define FEAT_ 2048

typedef unsigned short u16;
typedef __attribute__((ext_vector_type(8))) short bf16x8;
typedef __attribute__((ext_vector_type(4))) float fx4;

#define MFMA16 __builtin_amdgcn_mfma_f32_16x16x32_bf16

__device__ __forceinline__ u16 f2b(float f){
  unsigned u = __builtin_bit_cast(unsigned, f);
  u += 0x7FFFu + ((u >> 16) & 1u);
  return (u16)(u >> 16);
}
__device__ __forceinline__ float b2f(u16 h){
  unsigned u = ((unsigned)h) << 16;
  return __builtin_bit_cast(float, u);
}
__device__ __forceinline__ float sigm(float x){ return 1.f/(1.f + __expf(-x)); }

// ================= merged prep (R16-proven) =================
#define PREP_BLOCKS 31670
__global__ void k_prep(const float* __restrict__ Wad, const float* __restrict__ We,
                       const float* __restrict__ W1f, const float* __restrict__ W2f,
                       const float* __restrict__ Wd,
                       const float* __restrict__ Wih0, const float* __restrict__ Whh0,
                       const float* __restrict__ Wih1, const float* __restrict__ Whh1,
                       const float* __restrict__ bih0, const float* __restrict__ bhh0,
                       const float* __restrict__ bih1, const float* __restrict__ bhh1,
                       const float* __restrict__ emb, const int* __restrict__ cap,
                       const float* __restrict__ feat,
                       u16* __restrict__ Wad16, u16* __restrict__ We16,
                       u16* __restrict__ W1_16, u16* __restrict__ W2pk,
                       unsigned* __restrict__ Wd2, u16* __restrict__ Wg0pk,
                       u16* __restrict__ W1ppk, float* __restrict__ bias0p,
                       float* __restrict__ bias1p, u16* __restrict__ embs16,
                       u16* __restrict__ fb16){
  int bid = blockIdx.x, tid = threadIdx.x;
  if (bid < 12288){
    int eid = bid*256 + tid;
    int j = eid & 7, l = (eid >> 3) & 63, frag = eid >> 9;
    int ks = frag % 12; int rest = frag / 12;
    int kw = rest & 3, q = (rest >> 2) & 3, s = rest >> 4;
    int n = q*512 + s*16 + (l & 15);
    int k = kw*384 + ks*32 + ((l >> 4) << 3) + j;
    float v = (k < 1024) ? Wih0[(size_t)n*1024 + k] : Whh0[(size_t)n*512 + (k - 1024)];
    Wg0pk[eid] = f2b(v);
  } else if (bid < 20480){
    int eid = (bid-12288)*256 + tid;
    int j = eid & 7, l = (eid >> 3) & 63, f = eid >> 9;
    int nf = f & 127, s = f >> 7;
    int np = nf*16 + (l & 15);
    int k = ((l >> 4) << 3) + j;
    int orig = ((np >> 4) & 3)*512 + (np >> 6)*16 + (np & 15);
    float v = (k < 16) ? Wih1[(size_t)orig*512 + s*16 + k]
                       : Whh1[(size_t)orig*512 + s*16 + (k - 16)];
    W1ppk[eid] = f2b(v);
  } else if (bid < 24230){
    int i = (bid-20480)*256 + tid;
    int l = i & 63, kc = (i >> 6) & 7, nf = i >> 9;
    int row = nf*16 + (l & 15);
    int col = kc*32 + (l >> 4)*8;
    const float4* s = (const float4*)(W2f + (size_t)row*256 + col);
    float4 a = s[0], b = s[1];
    ushort4* d = (ushort4*)(W2pk + (size_t)i*8);
    d[0] = make_ushort4(f2b(a.x), f2b(a.y), f2b(a.z), f2b(a.w));
    d[1] = make_ushort4(f2b(b.x), f2b(b.y), f2b(b.z), f2b(b.w));
  } else if (bid < 24742){
    int i = (bid-24230)*256 + tid;
    const float4* s = (const float4*)Wad + (size_t)i*2;
    float4 a = s[0], b = s[1];
    ushort4* d = (ushort4*)Wad16 + (size_t)i*2;
    d[0] = make_ushort4(f2b(a.x), f2b(a.y), f2b(a.z), f2b(a.w));
    d[1] = make_ushort4(f2b(b.x), f2b(b.y), f2b(b.z), f2b(b.w));
  } else if (bid < 24806){
    int i = (bid-24742)*256 + tid;
    const float4* s = (const float4*)We + (size_t)i*2;
    float4 a = s[0], b = s[1];
    ushort4* d = (ushort4*)We16 + (size_t)i*2;
    d[0] = make_ushort4(f2b(a.x), f2b(a.y), f2b(a.z), f2b(a.w));
    d[1] = make_ushort4(f2b(b.x), f2b(b.y), f2b(b.z), f2b(b.w));
  } else if (bid < 24870){
    int i = (bid-24806)*256 + tid;
    const float4* s = (const float4*)W1f + (size_t)i*2;
    float4 a = s[0], b = s[1];
    ushort4* d = (ushort4*)W1_16 + (size_t)i*2;
    d[0] = make_ushort4(f2b(a.x), f2b(a.y), f2b(a.z), f2b(a.w));
    d[1] = make_ushort4(f2b(b.x), f2b(b.y), f2b(b.z), f2b(b.w));
  } else if (bid < 25126){
    int i = (bid-24870)*256 + tid;
    int n = i & 255, kp = i >> 8;
    unsigned lo = f2b(Wd[n*512 + 2*kp]);
    unsigned hi = f2b(Wd[n*512 + 2*kp + 1]);
    Wd2[i] = lo | (hi << 16);
  } else if (bid < 25134){
    int n = (bid-25126)*256 + tid;
    int c = n & 15, q = (n >> 4) & 3, s = n >> 6;
    int orig = q*512 + s*16 + c;
    bias0p[n] = bih0[orig] + bhh0[orig];
  } else if (bid < 25142){
    int n = (bid-25134)*256 + tid;
    int c = n & 15, q = (n >> 4) & 3, s = n >> 6;
    int orig = q*512 + s*16 + c;
    bias1p[n] = bih1[orig] + bhh1[orig];
  } else if (bid < 25398){
    int r = (bid-25142)*4 + (tid >> 6), l = tid & 63;
    int t = r >> 5, b = r & 31;
    int c = cap[b*T_ + t];
    const float4* s = (const float4*)(emb + (size_t)c*E_) + l*2;
    float4 a = s[0], bb = s[1];
    ushort4* d = (ushort4*)(embs16 + (size_t)r*E_) + l*2;
    d[0] = make_ushort4(f2b(a.x), f2b(a.y), f2b(a.z), f2b(a.w));
    d[1] = make_ushort4(f2b(bb.x), f2b(bb.y), f2b(bb.z), f2b(bb.w));
  } else {
    int i = (bid-25398)*256 + tid;
    const float4* s = (const float4*)feat + (size_t)i*2;
    float4 a = s[0], b = s[1];
    ushort4* d = (ushort4*)fb16 + (size_t)i*2;
    d[0] = make_ushort4(f2b(a.x), f2b(a.y), f2b(a.z), f2b(a.w));
    d[1] = make_ushort4(f2b(b.x), f2b(b.y), f2b(b.z), f2b(b.w));
  }
}

// ============ split-K adapter GEMM: f32 partials, no bias/act ============
// grid = NKQ * (8*NQ*13); kq in high bits; inner decode XCD-swizzled as before.
template<int BM, int BN, int KS, int NQ, int NKQ>
__launch_bounds__(256)
__global__ void k_gemmSK(const u16* __restrict__ A, const u16* __restrict__ W,
                         float* __restrict__ outP, int M, int N, int K){
  constexpr int NI = BN/32, MI = BM/32, SEGS = KS/8;
  __shared__ __align__(16) u16 As[BM][KS+8];
  __shared__ __align__(16) u16 Bs[BN][KS+8];
  int f = blockIdx.x;
  int inner = 8*NQ*((M/BM + 7)/8);
  int kq = f / inner; f %= inner;
  int p8 = f & 7; int rest = f >> 3;
  int q = rest % NQ; int pHigh = rest / NQ;
  int p = pHigh*8 + p8;
  if (p*BM >= M) return;
  int m0 = p*BM, n0 = q*BN;
  int kper = K / NKQ;
  int kbeg = kq * kper, kend = kbeg + kper;
  int tid = threadIdx.x;
  int l = tid & 63, w = tid >> 6;
  int wr = w >> 1, wc = w & 1;
  fx4 acc[MI][NI];
  #pragma unroll
  for (int i=0;i<MI;i++)
    #pragma unroll
    for (int j=0;j<NI;j++) acc[i][j] = (fx4){0.f,0.f,0.f,0.f};
  int lr = l & 15, lg = l >> 4;
  for (int k0 = kbeg; k0 < kend; k0 += KS){
    #pragma unroll
    for (int it=0; it<BM*SEGS/256; ++it){
      int flat = it*256 + tid, rr = flat/SEGS, cs = (flat%SEGS)*8;
      *(uint4*)&As[rr][cs] = *(const uint4*)(A + (size_t)(m0+rr)*K + k0 + cs);
    }
    #pragma unroll
    for (int it=0; it<BN*SEGS/256; ++it){
      int flat = it*256 + tid, rr = flat/SEGS, cs = (flat%SEGS)*8;
      *(uint4*)&Bs[rr][cs] = *(const uint4*)(W + (size_t)(n0+rr)*K + k0 + cs);
    }
    __syncthreads();
    #pragma unroll
    for (int kk=0; kk<KS/32; ++kk){
      bf16x8 av[MI], bv[NI];
      #pragma unroll
      for (int mi=0; mi<MI; mi++) av[mi] = *(const bf16x8*)&As[wr*(BM/2) + mi*16 + lr][kk*32 + lg*8];
      #pragma unroll
      for (int ni=0; ni<NI; ni++) bv[ni] = *(const bf16x8*)&Bs[wc*(BN/2) + ni*16 + lr][kk*32 + lg*8];
      #pragma unroll
      for (int mi=0; mi<MI; mi++)
        #pragma unroll
        for (int ni=0; ni<NI; ni++)
          acc[mi][ni] = MFMA16(av[mi], bv[ni], acc[mi][ni], 0, 0, 0);
    }
    __syncthreads();
  }
  #pragma unroll
  for (int mi=0; mi<MI; mi++)
    #pragma unroll
    for (int ni=0; ni<NI; ni++){
      int col = n0 + wc*(BN/2) + ni*16 + lr;
      #pragma unroll
      for (int reg=0; reg<4; reg++){
        int rowm = m0 + wr*(BM/2) + mi*16 + lg*4 + reg;
        outP[((size_t)kq*M + rowm)*N + col] = acc[mi][ni][reg];
      }
    }
}

// ============ encoder GEMM (att1), XCD-panel swizzle (R16-proven) ============
template<int MODE, int BM, int BN, int KS, int NQ>
__launch_bounds__(256)
__global__ void k_gemm(const u16* __restrict__ A, const u16* __restrict__ W,
                       const float* __restrict__ bias, u16* __restrict__ outB,
                       int M, int N, int K){
  constexpr int NI = BN/32, MI = BM/32, SEGS = KS/8;
  __shared__ __align__(16) u16 As[BM][KS+8];
  __shared__ __align__(16) u16 Bs[BN][KS+8];
  int f = blockIdx.x;
  int p8 = f & 7; int rest = f >> 3;
  int q = rest % NQ; int pHigh = rest / NQ;
  int p = pHigh*8 + p8;
  if (p*BM >= M) return;
  int m0 = p*BM, n0 = q*BN;
  int tid = threadIdx.x;
  int l = tid & 63, w = tid >> 6;
  int wr = w >> 1, wc = w & 1;
  fx4 acc[MI][NI];
  #pragma unroll
  for (int i=0;i<MI;i++)
    #pragma unroll
    for (int j=0;j<NI;j++) acc[i][j] = (fx4){0.f,0.f,0.f,0.f};
  int lr = l & 15, lg = l >> 4;
  for (int k0 = 0; k0 < K; k0 += KS){
    #pragma unroll
    for (int it=0; it<BM*SEGS/256; ++it){
      int flat = it*256 + tid, rr = flat/SEGS, cs = (flat%SEGS)*8;
      *(uint4*)&As[rr][cs] = *(const uint4*)(A + (size_t)(m0+rr)*K + k0 + cs);
    }
    uint4 z = {0u,0u,0u,0u};
    #pragma unroll
    for (int it=0; it<BN*SEGS/256; ++it){
      int flat = it*256 + tid, rr = flat/SEGS, cs = (flat%SEGS)*8;
      int rb = n0 + rr;
      *(uint4*)&Bs[rr][cs] = (rb < N) ? *(const uint4*)(W + (size_t)rb*K + k0 + cs) : z;
    }
    __syncthreads();
    #pragma unroll
    for (int kk=0; kk<KS/32; ++kk){
      bf16x8 av[MI], bv[NI];
      #pragma unroll
      for (int mi=0; mi<MI; mi++) av[mi] = *(const bf16x8*)&As[wr*(BM/2) + mi*16 + lr][kk*32 + lg*8];
      #pragma unroll
      for (int ni=0; ni<NI; ni++) bv[ni] = *(const bf16x8*)&Bs[wc*(BN/2) + ni*16 + lr][kk*32 + lg*8];
      #pragma unroll
      for (int mi=0; mi<MI; mi++)
        #pragma unroll
        for (int ni=0; ni<NI; ni++)
          acc[mi][ni] = MFMA16(av[mi], bv[ni], acc[mi][ni], 0, 0, 0);
    }
    __syncthreads();
  }
  #pragma unroll
  for (int mi=0; mi<MI; mi++)
    #pragma unroll
    for (int ni=0; ni<NI; ni++){
      int col = n0 + wc*(BN/2) + ni*16 + lr;
      if (col >= N) continue;
      float bvs = bias[col];
      #pragma unroll
      for (int reg=0; reg<4; reg++){
        int rowm = m0 + wr*(BM/2) + mi*16 + lg*4 + reg;
        float v = acc[mi][ni][reg] + bvs;
        if (MODE == 0) v = fmaxf(v, 0.f);
        outB[(size_t)rowm*N + col] = f2b(v);
      }
    }
}

// ---------------- LayerNorm 512 + split-K reduce + bias + relu (f32 partials in) ----------------
__global__ void k_ln1(const float* __restrict__ preP, const float* __restrict__ bad,
                      const float* __restrict__ g, const float* __restrict__ bt,
                      u16* __restrict__ enc){
  int row = blockIdx.x; int l = threadIdx.x;
  int c0 = l*8;
  float x[8];
  {
    const float4* p0 = (const float4*)(preP + ((size_t)0*6272 + row)*E_ + c0);
    const float4* p1 = (const float4*)(preP + ((size_t)1*6272 + row)*E_ + c0);
    const float4* p2 = (const float4*)(preP + ((size_t)2*6272 + row)*E_ + c0);
    const float4* p3 = (const float4*)(preP + ((size_t)3*6272 + row)*E_ + c0);
    float4 a0 = p0[0], b0 = p0[1];
    float4 a1 = p1[0], b1 = p1[1];
    float4 a2 = p2[0], b2 = p2[1];
    float4 a3 = p3[0], b3 = p3[1];
    x[0] = a0.x+a1.x+a2.x+a3.x; x[1] = a0.y+a1.y+a2.y+a3.y;
    x[2] = a0.z+a1.z+a2.z+a3.z; x[3] = a0.w+a1.w+a2.w+a3.w;
    x[4] = b0.x+b1.x+b2.x+b3.x; x[5] = b0.y+b1.y+b2.y+b3.y;
    x[6] = b0.z+b1.z+b2.z+b3.z; x[7] = b0.w+b1.w+b2.w+b3.w;
  }
  float s = 0.f;
  #pragma unroll
  for (int i=0;i<8;i++){ x[i] = fmaxf(x[i] + bad[c0+i], 0.f); s += x[i]; }
  #pragma unroll
  for (int off=32; off; off>>=1) s += __shfl_xor(s, off, 64);
  float mean = s * (1.f/512.f);
  float vs = 0.f;
  #pragma unroll
  for (int i=0;i<8;i++){ float d = x[i]-mean; vs += d*d; }
  #pragma unroll
  for (int off=32; off; off>>=1) vs += __shfl_xor(vs, off, 64);
  float inv = rsqrtf(vs*(1.f/512.f) + 1e-5f);
  u16 o[8];
  #pragma unroll
  for (int i=0;i<8;i++) o[i] = f2b((x[i]-mean)*inv*g[c0+i] + bt[c0+i]);
  ushort4* d = (ushort4*)(enc + (size_t)row*E_ + c0);
  d[0] = make_ushort4(o[0],o[1],o[2],o[3]);
  d[1] = make_ushort4(o[4],o[5],o[6],o[7]);
}

// ---------------- W1 GEMM + LN + relu (R13-proven) ----------------
__device__ __forceinline__ void w1ln_block(const u16* __restrict__ h1all,
    const u16* __restrict__ W1, const float* __restrict__ b1,
    const float* __restrict__ g1v, const float* __restrict__ bb1,
    u16* __restrict__ hid, int u, int tid, float* red2, float* mv){
  int l = tid & 63, w = tid >> 6, lr = l & 15, lg = l >> 4;
  fx4 acc[2] = {{0,0,0,0},{0,0,0,0}};
  for (int k0 = 0; k0 < 512; k0 += 32){
    bf16x8 bv  = *(const bf16x8*)(W1 + (size_t)(w*16+lr)*512 + k0 + lg*8);
    bf16x8 av0 = *(const bf16x8*)(h1all + ((size_t)lr*T_ + u)*512 + k0 + lg*8);
    bf16x8 av1 = *(const bf16x8*)(h1all + ((size_t)(16+lr)*T_ + u)*512 + k0 + lg*8);
    acc[0] = MFMA16(av0, bv, acc[0], 0,0,0);
    acc[1] = MFMA16(av1, bv, acc[1], 0,0,0);
  }
  int col = w*16 + lr;
  float bc = b1[col];
  float val[2][4], s1[2][4], s2[2][4];
  #pragma unroll
  for (int mi=0;mi<2;mi++)
    #pragma unroll
    for (int reg=0;reg<4;reg++){
      float v = acc[mi][reg] + bc;
      val[mi][reg] = v; s1[mi][reg] = v; s2[mi][reg] = v*v;
    }
  #pragma unroll
  for (int off=1; off<16; off<<=1){
    #pragma unroll
    for (int mi=0;mi<2;mi++)
      #pragma unroll
      for (int reg=0;reg<4;reg++){
        s1[mi][reg] += __shfl_xor(s1[mi][reg], off, 64);
        s2[mi][reg] += __shfl_xor(s2[mi][reg], off, 64);
      }
  }
  if (lr == 0){
    #pragma unroll
    for (int mi=0;mi<2;mi++)
      #pragma unroll
      for (int reg=0;reg<4;reg++){
        int row = mi*16 + lg*4 + reg;
        red2[(0*16 + w)*32 + row] = s1[mi][reg];
        red2[(16   + w)*32 + row] = s2[mi][reg];
      }
  }
  __syncthreads();
  if (tid < 64){
    int which = tid >> 5, row = tid & 31;
    float s = 0.f;
    #pragma unroll
    for (int ww=0; ww<16; ++ww) s += red2[(which*16 + ww)*32 + row];
    mv[which*32 + row] = s;
  }
  __syncthreads();
  #pragma unroll
  for (int mi=0;mi<2;mi++)
    #pragma unroll
    for (int reg=0;reg<4;reg++){
      int row = mi*16 + lg*4 + reg;
      float mean = mv[row] * (1.f/256.f);
      float var  = mv[32+row] * (1.f/256.f) - mean*mean;
      float inv  = rsqrtf(var + 1e-5f);
      float o = fmaxf((val[mi][reg]-mean)*inv*g1v[col] + bb1[col], 0.f);
      hid[((size_t)u*32 + row)*256 + col] = f2b(o);
    }
}

__launch_bounds__(1024)
__global__ void k_w1(const u16* __restrict__ h1all, const u16* __restrict__ W1_16,
                     const float* __restrict__ b1, const float* __restrict__ g1v,
                     const float* __restrict__ bb1, u16* __restrict__ hid16){
  __shared__ float red2[1024];
  __shared__ float mv[64];
  w1ln_block(h1all, W1_16, b1, g1v, bb1, hid16, blockIdx.x, threadIdx.x, red2, mv);
}

// ---------------- head (R13-proven) ----------------
__launch_bounds__(1024)
__global__ void k_head(const u16* __restrict__ hid, const u16* __restrict__ W2pk,
                       const float* __restrict__ b2, float* __restrict__ out){
  __shared__ __align__(16) union { u16 hA[32][264]; float Cs[32][260]; } S;
  int c = blockIdx.x, uh = blockIdx.y, tid = threadIdx.x;
  int l = tid & 63, w = tid >> 6, lr = l & 15, lg = l >> 4;
  int nf = c*16 + w;
  bool valid = nf < 1875;
  bf16x8 bw[8];
  if (valid){
    const u16* wp = W2pk + (size_t)nf*4096 + l*8;
    #pragma unroll
    for (int k0=0;k0<8;k0++) bw[k0] = *(const bf16x8*)(wp + k0*512);
  }
  int srow = tid >> 5, scc = (tid & 31)*8;
  int col0 = c*256 + scc;
  float bb[8];
  #pragma unroll
  for (int j=0;j<8;j++) bb[j] = (col0 + j < V_) ? b2[col0 + j] : 0.f;

  for (int ui=0; ui<16; ++ui){
    int u = uh*16 + ui;
    { int arow = tid >> 5, ak = (tid & 31)*8;
      *(uint4*)&S.hA[arow][ak] = *(const uint4*)(hid + ((size_t)u*32 + arow)*256 + ak); }
    __syncthreads();
    fx4 acc0 = {0,0,0,0}, acc1 = {0,0,0,0};
    if (valid){
      #pragma unroll
      for (int k0=0;k0<8;k0++){
        bf16x8 av0 = *(const bf16x8*)&S.hA[lr][k0*32 + lg*8];
        bf16x8 av1 = *(const bf16x8*)&S.hA[16+lr][k0*32 + lg*8];
        acc0 = MFMA16(av0, bw[k0], acc0, 0,0,0);
        acc1 = MFMA16(av1, bw[k0], acc1, 0,0,0);
      }
    }
    __syncthreads();
    #pragma unroll
    for (int reg=0; reg<4; ++reg){
      S.Cs[lg*4+reg][w*16+lr]    = acc0[reg];
      S.Cs[16+lg*4+reg][w*16+lr] = acc1[reg];
    }
    __syncthreads();
    if (col0 + 8 <= V_){
      float4 v0, v1;
      v0.x = fminf(fmaxf(S.Cs[srow][scc+0] + bb[0], -10.f), 10.f);
      v0.y = fminf(fmaxf(S.Cs[srow][scc+1] + bb[1], -10.f), 10.f);
      v0.z = fminf(fmaxf(S.Cs[srow][scc+2] + bb[2], -10.f), 10.f);
      v0.w = fminf(fmaxf(S.Cs[srow][scc+3] + bb[3], -10.f), 10.f);
      v1.x = fminf(fmaxf(S.Cs[srow][scc+4] + bb[4], -10.f), 10.f);
      v1.y = fminf(fmaxf(S.Cs[srow][scc+5] + bb[5], -10.f), 10.f);
      v1.z = fminf(fmaxf(S.Cs[srow][scc+6] + bb[6], -10.f), 10.f);
      v1.w = fminf(fmaxf(S.Cs[srow][scc+7] + bb[7], -10.f), 10.f);
      float* o = out + ((size_t)srow*T_ + u)*V_ + col0;
      *(float4*)o = v0; *(float4*)(o+4) = v1;
    }
    __syncthreads();
  }
}

// ---------------- LY (R8-proven; part1 unroll 8) ----------------
__launch_bounds__(1024)
__global__ void k_ly(const float* __restrict__ part1, const float* __restrict__ bias1p,
                     float* __restrict__ c1buf, u16* __restrict__ h1all,
                     const unsigned* __restrict__ Wd2, const float* __restrict__ bd,
                     const u16* __restrict__ att1b, const u16* __restrict__ enc16,
                     const float* __restrict__ Wf, const float* __restrict__ bfp,
                     const u16* __restrict__ embs, u16* __restrict__ xh0cur, int t){
  int b = blockIdx.x, tid = threadIdx.x;
  int l = tid & 63, wid = tid >> 6;
  __shared__ float g1s[2048];
  __shared__ float h1s[512];
  __shared__ float a2p[4][256];
  __shared__ float a2[256], ev[256], red[8], wfv[256], bdv[256];
  __shared__ float cb[4][256][2];
  if (tid < 256){ wfv[tid] = Wf[tid]; bdv[tid] = bd[tid]; }
  float bf0 = bfp[0];

  if (t > 0){
    float acc0 = bias1p[tid], acc1 = bias1p[tid + 1024];
    #pragma unroll 8
    for (int s2=0; s2<32; ++s2){
      const float* pp = part1 + ((size_t)(s2*32 + b))*2048;
      acc0 += pp[tid];
      acc1 += pp[tid + 1024];
    }
    g1s[tid] = acc0; g1s[tid + 1024] = acc1;
    __syncthreads();
    if (tid < 512){
      int h = tid, s4 = h >> 4, c = h & 15, base = s4*64 + c;
      float gi = g1s[base], gf = g1s[base+16], gg = g1s[base+32], go = g1s[base+48];
      float cold = c1buf[b*512 + h];
      float cn = sigm(gf)*cold + sigm(gi)*tanhf(gg);
      c1buf[b*512 + h] = cn;
      float hn = sigm(go)*tanhf(cn);
      h1s[h] = hn;
      h1all[((size_t)b*T_ + (t-1))*512 + h] = f2b(hn);
    }
  } else {
    if (tid < 512) h1s[tid] = 0.f;
  }
  __syncthreads();
  if (t >= T_) return;

  {
    int n = tid & 255, kq = tid >> 8;
    float acc = 0.f;
    const unsigned* wp = Wd2 + (size_t)kq*64*256 + n;
    #pragma unroll 8
    for (int kp2 = 0; kp2 < 64; ++kp2){
      unsigned wv = wp[(size_t)kp2*256];
      int k0 = (kq*64 + kp2)*2;
      acc += h1s[k0]   * b2f((u16)(wv & 0xFFFFu))
           + h1s[k0+1] * b2f((u16)(wv >> 16));
    }
    a2p[kq][n] = acc;
  }
  __syncthreads();
  if (tid < 256) a2[tid] = a2p[0][tid] + a2p[1][tid] + a2p[2][tid] + a2p[3][tid] + bdv[tid];
  __syncthreads();
  for (int pi = 0; pi < 13; ++pi){
    int p = pi*16 + wid;
    if (p < P_){
      ushort4 av4 = *(const ushort4*)(att1b + (size_t)(b*P_ + p)*A_ + l*4);
      int j0 = l*4;
      float sum = fmaxf(b2f(av4.x)+a2[j0],  0.f)*wfv[j0]
                + fmaxf(b2f(av4.y)+a2[j0+1],0.f)*wfv[j0+1]
                + fmaxf(b2f(av4.z)+a2[j0+2],0.f)*wfv[j0+2]
                + fmaxf(b2f(av4.w)+a2[j0+3],0.f)*wfv[j0+3];
      #pragma unroll
      for (int off=32; off; off>>=1) sum += __shfl_xor(sum, off, 64);
      if (l == 0) ev[p] = sum + bf0;
    }
  }
  __syncthreads();
  if (tid < 256){
    float v = (tid < P_) ? ev[tid] : -1e30f;
    float m = v;
    #pragma unroll
    for (int off=32; off; off>>=1) m = fmaxf(m, __shfl_xor(m, off, 64));
    if (l == 0) red[wid] = m;
  }
  __syncthreads();
  float mg = fmaxf(fmaxf(red[0],red[1]), fmaxf(red[2],red[3]));
  if (tid < 256){
    float ex = (tid < P_) ? __expf(ev[tid] - mg) : 0.f;
    float ss = ex;
    #pragma unroll
    for (int off=32; off; off>>=1) ss += __shfl_xor(ss, off, 64);
    if (l == 0) red[4+wid] = ss;
    ev[tid] = ex;
  }
  __syncthreads();
  float inv = 1.f/(red[4]+red[5]+red[6]+red[7]);
  {
    int j = tid & 255, pq = tid >> 8;
    float A0 = 0.f, A1 = 0.f;
    const unsigned* ep = (const unsigned*)enc16 + ((size_t)b*P_ + pq*49)*256 + j;
    #pragma unroll 7
    for (int pi = 0; pi < 49; ++pi){
      unsigned vv = ep[(size_t)pi*256];
      float al = ev[pq*49 + pi];
      A0 += al * b2f((u16)(vv & 0xFFFFu));
      A1 += al * b2f((u16)(vv >> 16));
    }
    cb[pq][j][0] = A0; cb[pq][j][1] = A1;
  }
  __syncthreads();
  if (tid < 256){
    float c0 = (cb[0][tid][0]+cb[1][tid][0]+cb[2][tid][0]+cb[3][tid][0]) * inv;
    float c1 = (cb[0][tid][1]+cb[1][tid][1]+cb[2][tid][1]+cb[3][tid][1]) * inv;
    unsigned o = (unsigned)f2b(c0) | (((unsigned)f2b(c1)) << 16);
    *((unsigned*)(xh0cur + (size_t)b*1536 + 512) + tid) = o;
    ((unsigned*)(xh0cur + (size_t)b*1536))[tid] =
        ((const unsigned*)(embs + (size_t)(t*32+b)*E_))[tid];
  }
}

// ---------------- LX: 64 blocks = (slice s, batch-half) (R16-proven) ----------------
__launch_bounds__(1024)
__global__ void k_lx(const u16* __restrict__ xh0cur, u16* __restrict__ xh0nxt,
                     const u16* __restrict__ Wg0pk, const float* __restrict__ bias0p,
                     const u16* __restrict__ W1ppk, const u16* __restrict__ h1all,
                     float* __restrict__ c0buf, float* __restrict__ part1, int t){
  __shared__ float part[16][16][16];
  __shared__ float gsum[4][16][16];
  __shared__ __align__(16) u16 As[16][40];
  int tid = threadIdx.x;
  int s = blockIdx.x >> 1, half = blockIdx.x & 1;
  int l = tid & 63, kw = tid >> 6, lr = l & 15, lg = l >> 4;
  int babs = half*16 + lr;

  bf16x8 a[3];
  #pragma unroll
  for (int ks=0;ks<3;ks++)
    a[ks] = *(const bf16x8*)(xh0cur + (size_t)babs*1536 + kw*96 + ks*32 + lg*8);
  if (tid < 128){
    int bb = tid >> 3, kk = (tid & 7)*2;
    unsigned hv = 0;
    if (t > 0) hv = *(const unsigned*)(h1all + ((size_t)(half*16+bb)*T_ + (t-1))*512 + s*16 + kk);
    *(unsigned*)&As[bb][16+kk] = hv;
  }
  for (int q=0;q<4;q++){
    fx4 acc0 = (fx4){0,0,0,0};
    const u16* wp = Wg0pk + (size_t)(((s*4+q)*4 + (kw>>2))*12 + (kw&3)*3)*512 + l*8;
    #pragma unroll
    for (int ks=0;ks<3;ks++){
      bf16x8 bf8 = *(const bf16x8*)(wp + ks*512);
      acc0 = MFMA16(a[ks], bf8, acc0, 0,0,0);
    }
    #pragma unroll
    for (int reg=0;reg<4;reg++)
      part[kw][lg*4+reg][lr] = acc0[reg];
    __syncthreads();
    if (tid < 256){
      int bb = tid >> 4, c = tid & 15;
      float g = bias0p[s*64 + q*16 + c];
      #pragma unroll
      for (int kw2=0; kw2<16; ++kw2) g += part[kw2][bb][c];
      gsum[q][bb][c] = g;
    }
    __syncthreads();
  }
  if (tid < 256){
    int bb = tid >> 4, c = tid & 15;
    int h = s*16 + c, ba = half*16 + bb;
    float gi = gsum[0][bb][c], gf = gsum[1][bb][c], gg = gsum[2][bb][c], go = gsum[3][bb][c];
    float cold = c0buf[ba*512 + h];
    float cn = sigm(gf)*cold + sigm(gi)*tanhf(gg);
    c0buf[ba*512 + h] = cn;
    u16 hb = f2b(sigm(go)*tanhf(cn));
    xh0nxt[(size_t)ba*1536 + 1024 + h] = hb;
    As[bb][c] = hb;
  }
  __syncthreads();
  bf16x8 pa0 = *(const bf16x8*)&As[lr][lg*8];
  #pragma unroll 2
  for (int i=0;i<8;i++){
    int nf = kw*8 + i;
    bf16x8 bf8 = *(const bf16x8*)(W1ppk + (size_t)(s*128 + nf)*512 + l*8);
    fx4 A0 = MFMA16(pa0, bf8, (fx4){0,0,0,0}, 0,0,0);
    float* o = part1 + ((size_t)s*32 + half*16)*2048 + nf*16 + lr;
    #pragma unroll
    for (int reg=0;reg<4;reg++)
      o[(size_t)(lg*4+reg)*2048] = A0[reg];
  }
}

extern "C" void kernel_launch(void* const* d_in, const int* in_sizes, int n_in,
                              void* d_out, int out_size, void* d_ws, size_t ws_size,
                              hipStream_t stream){
  (void)in_sizes; (void)n_in; (void)out_size; (void)ws_size;
  const float* features = (const float*)d_in[0];
  const int*   captions = (const int*)d_in[1];
  const float* Wad  = (const float*)d_in[2];
  const float* bad  = (const float*)d_in[3];
  const float* g_ad = (const float*)d_in[4];
  const float* b_ad = (const float*)d_in[5];
  const float* We   = (const float*)d_in[6];
  const float* be   = (const float*)d_in[7];
  const float* Wd   = (const float*)d_in[8];
  const float* bd   = (const float*)d_in[9];
  const float* Wf   = (const float*)d_in[10];
  const float* bfp  = (const float*)d_in[11];
  const float* emb  = (const float*)d_in[12];
  const float* W_ih0 = (const float*)d_in[13];
  const float* W_hh0 = (const float*)d_in[14];
  const float* b_ih0 = (const float*)d_in[15];
  const float* b_hh0 = (const float*)d_in[16];
  const float* W_ih1 = (const float*)d_in[17];
  const float* W_hh1 = (const float*)d_in[18];
  const float* b_ih1 = (const float*)d_in[19];
  const float* b_hh1 = (const float*)d_in[20];
  const float* W1  = (const float*)d_in[21];
  const float* b1  = (const float*)d_in[22];
  const float* g1  = (const float*)d_in[23];
  const float* bb1 = (const float*)d_in[24];
  const float* W2  = (const float*)d_in[25];
  const float* b2  = (const float*)d_in[26];
  float* out = (float*)d_out;

  char* wsb = (char*)d_ws;
  size_t off = 0;
  auto alloc = [&](size_t bytes)->char*{
    char* p = wsb + off; off += (bytes + 255) & ~(size_t)255; return p;
  };
  u16* fb16    = (u16*)alloc((size_t)6272*2048*2);
  u16* Wad16   = (u16*)alloc((size_t)512*2048*2);
  u16* We16    = (u16*)alloc((size_t)256*512*2);
  u16* W1_16   = (u16*)alloc((size_t)256*512*2);
  u16* W2pk    = (u16*)alloc((size_t)1875*8*512*2);
  unsigned* Wd2 = (unsigned*)alloc((size_t)256*256*4);
  u16* Wg0pk   = (u16*)alloc((size_t)2048*1536*2);
  u16* W1ppk   = (u16*)alloc((size_t)32*128*512*2);
  float* bias0p = (float*)alloc(2048*4);
  float* bias1p = (float*)alloc(2048*4);
  u16* embs16  = (u16*)alloc((size_t)1024*512*2);
  u16* enc16   = (u16*)alloc((size_t)6272*512*2);
  u16* att1_16 = (u16*)alloc((size_t)6272*256*2);
  u16* xh0     = (u16*)alloc((size_t)2*32*1536*2);   // zeroed region start
  float* c0buf = (float*)alloc(32*512*4);
  float* c1buf = (float*)alloc(32*512*4);            // zeroed region end
  float* part1 = (float*)alloc((size_t)32*32*2048*4);
  u16* h1all16 = (u16*)alloc((size_t)1024*512*2);
  u16* hid16   = (u16*)alloc((size_t)1024*256*2);
  float* pre32f = (float*)alloc((size_t)4*6272*512*4);  // split-K partials (51.4 MB)

  hipMemsetAsync(xh0, 0, 196608 + 65536 + 65536, stream);

  // prep: one merged launch (includes features->bf16)
  k_prep<<<PREP_BLOCKS,256,0,stream>>>(Wad, We, W1, W2, Wd,
                                       W_ih0, W_hh0, W_ih1, W_hh1,
                                       b_ih0, b_hh0, b_ih1, b_hh1,
                                       emb, captions, features,
                                       Wad16, We16, W1_16, W2pk, Wd2,
                                       Wg0pk, W1ppk, bias0p, bias1p, embs16, fb16);

  // adapter: split-K 4-way (3328 blocks, 8 K-iters each) -> f32 partials
  k_gemmSK<64,64,64,8,4><<<3328,256,0,stream>>>(fb16, Wad16, pre32f, 6272, 512, 2048);
  // ln1: reduce 4 partials + bias + relu + LN
  k_ln1<<<6272,64,0,stream>>>(pre32f, bad, g_ad, b_ad, enc16);
  k_gemm<1,64,64,64,4><<<416,256,0,stream>>>(enc16, We16, be, att1_16, 6272, 256, 512);

  // recurrence: k_ly 32 blocks, k_lx 64 blocks
  u16* xb[2] = { xh0, xh0 + 32*1536 };
  for (int t = 0; t < T_; ++t){
    k_ly<<<32,1024,0,stream>>>(part1, bias1p, c1buf, h1all16, Wd2, bd,
                               att1_16, enc16, Wf, bfp, embs16, xb[t&1], t);
    k_lx<<<64,1024,0,stream>>>(xb[t&1], xb[1-(t&1)], Wg0pk, bias0p,
                               W1ppk, h1all16, c0buf, part1, t);
  }
  // final finish: h1(31) -> h1all
  k_ly<<<32,1024,0,stream>>>(part1, bias1p, c1buf, h1all16, Wd2, bd,
                             att1_16, enc16, Wf, bfp, embs16, xb[0], T_);

  // tail: fused W1+LN+relu, then register-resident packed-W2 head
  k_w1<<<32,1024,0,stream>>>(h1all16, W1_16, b1, g1, bb1, hid16);
  k_head<<<dim3(118,2),1024,0,stream>>>(hid16, W2pk, b2, out);
}